// Round 13
// baseline (1825.247 us; speedup 1.0000x reference)
//
#include <hip/hip_runtime.h>
#include <stdint.h>

// FlashbackPlusPlus: embed->GRU->spatiotemporal causal attention->FC
// S=256 U=64 H=256 V=10000
#define S_LEN 256
#define U_LEN 64
#define H_DIM 256
#define V_DIM 10000
#define Y_ELEMS 163840000LL  // S*U*V

typedef short bf16x8 __attribute__((ext_vector_type(8)));
typedef float f32x4 __attribute__((ext_vector_type(4)));

__device__ __forceinline__ short f2bf(float f) {
  union { float f; uint32_t u; } v; v.f = f;
  uint32_t r = v.u + 0x7FFFu + ((v.u >> 16) & 1u);  // RNE
  return (short)(r >> 16);
}
__device__ __forceinline__ float bf2f(short s) {
  union { uint32_t u; float f; } v; v.u = ((uint32_t)(uint16_t)s) << 16;
  return v.f;
}

// global -> LDS async copy, 16B per lane. LDS dest = wave-uniform base + lane*16.
__device__ __forceinline__ void gload_lds16(const void* g, void* l) {
  __builtin_amdgcn_global_load_lds(
      (const __attribute__((address_space(1))) char*)(uintptr_t)g,
      (__attribute__((address_space(3))) char*)(uintptr_t)l, 16, 0, 0);
}

// ---------------------------------------------------------------------------
// prep: f32->bf16 weight conversions + active-user embedding gather + W_hh
// fragment pack (fragment-linear so the GRU preamble is coalesced dwordx4).
// ---------------------------------------------------------------------------
__global__ __launch_bounds__(256) void fpp_prep(
    const float* __restrict__ enc_W, const float* __restrict__ W_ih,
    const float* __restrict__ fc_W, const float* __restrict__ user_W,
    const float* __restrict__ W_hh, const int* __restrict__ active_user,
    short* __restrict__ encWb, short* __restrict__ WihB,
    short* __restrict__ fcWb, short* __restrict__ uWb,
    short* __restrict__ WhhFrag) {
  const int tid = blockIdx.x * 256 + threadIdx.x;
  const int stride = gridDim.x * 256;
  for (int i = tid; i < V_DIM * H_DIM; i += stride) encWb[i] = f2bf(enc_W[i]);
  for (int i = tid; i < 3 * H_DIM * H_DIM; i += stride) WihB[i] = f2bf(W_ih[i]);
  for (int i = tid; i < V_DIM * 2 * H_DIM; i += stride) fcWb[i] = f2bf(fc_W[i]);
  // uWb[u][k] = user_W[active_user[u]][k]  (64 x 256 bf16)
  for (int i = tid; i < 64 * 256; i += stride) {
    const int u = i >> 8, k = i & 255;
    uWb[i] = f2bf(user_W[(int64_t)active_user[u] * 256 + k]);
  }
  // WhhFrag[i], i = (((wv*6+tt)*8+kc)*64+lane)*8+j ; holds W_hh[n][k] bf16 with
  // n = (tt>>1)*256 + 32*wv + (tt&1)*16 + (lane&15), k = kc*32 + (lane>>4)*8 + j
  for (int i = tid; i < 768 * 256; i += stride) {
    const int j = i & 7, ln = (i >> 3) & 63, kc = (i >> 9) & 7, t12 = i >> 12;
    const int tt = t12 % 6, wvv = t12 / 6;
    const int n = (tt >> 1) * 256 + 32 * wvv + (tt & 1) * 16 + (ln & 15);
    const int k = kc * 32 + (ln >> 4) * 8 + j;
    WhhFrag[i] = f2bf(W_hh[n * 256 + k]);
  }
}

// ---------------------------------------------------------------------------
// GEMM 128x128 (R11, passing) -- used for gemm1 (gi pair-packed) and gemm_u.
// OMODE: 0 = f32 linear, 2 = bf16 gi pair-packed
// ---------------------------------------------------------------------------
template <int OMODE>
__global__ __launch_bounds__(256) void fpp_gemm_bt(
    const short* __restrict__ A, const short* __restrict__ B, void* __restrict__ C,
    const float* __restrict__ bias1, const float* __restrict__ bias2, int bias2_limit,
    const float* __restrict__ rowbias,
    int M, int N, int K, int lda, int ldb, int ldc,
    int MT, int NT, int SUPER, int XCD) {
  int bid = blockIdx.x;
  if (XCD) {
    const int nx = gridDim.x >> 3;
    bid = (bid & 7) * nx + (bid >> 3);
  }
  const int per_super = SUPER * NT;
  const int srow = bid / per_super;
  const int rrem = bid - srow * per_super;
  const int mi = srow * SUPER + (rrem % SUPER);
  const int ni = rrem / SUPER;
  const int m0 = mi * 128, n0 = ni * 128;

  __shared__ __attribute__((aligned(16))) short As[2][128 * 64];
  __shared__ __attribute__((aligned(16))) short Bs[2][128 * 64];

  const int tid = threadIdx.x;
  const int lane = tid & 63;
  const int wv = tid >> 6;
  const int wr = wv >> 1, wc = wv & 1;

  f32x4 acc[4][4];
#pragma unroll
  for (int a_ = 0; a_ < 4; ++a_)
#pragma unroll
    for (int b_ = 0; b_ < 4; ++b_) acc[a_][b_] = f32x4{0.f, 0.f, 0.f, 0.f};

  auto stage = [&](int buf, int k0) {
#pragma unroll
    for (int c = 0; c < 4; ++c) {
      const int chunk = c * 256 + tid;
      const int row = chunk >> 3, kc8 = chunk & 7;
      int gr = m0 + row; gr = (gr < M) ? gr : (M - 1);
      gload_lds16(A + (int64_t)gr * lda + k0 + kc8 * 8,
                  (char*)&As[buf][0] + (c * 256 + wv * 64) * 16);
    }
#pragma unroll
    for (int c = 0; c < 4; ++c) {
      const int chunk = c * 256 + tid;
      const int row = chunk >> 3, kc8 = chunk & 7;
      int gn = n0 + row; gn = (gn < N) ? gn : (N - 1);
      gload_lds16(B + (int64_t)gn * ldb + k0 + kc8 * 8,
                  (char*)&Bs[buf][0] + (c * 256 + wv * 64) * 16);
    }
  };

  const int nk = K >> 6;
  stage(0, 0);
  asm volatile("s_waitcnt vmcnt(0)" ::: "memory");
  __syncthreads();
  for (int ks = 0; ks < nk; ++ks) {
    const int cur = ks & 1;
    if (ks + 1 < nk) stage(cur ^ 1, (ks + 1) << 6);
#pragma unroll
    for (int kk = 0; kk < 2; ++kk) {
      bf16x8 af[4], bfr[4];
#pragma unroll
      for (int mt = 0; mt < 4; ++mt)
        af[mt] = *(const bf16x8*)&As[cur][(wr * 64 + mt * 16 + (lane & 15)) * 64 +
                                          kk * 32 + (lane >> 4) * 8];
#pragma unroll
      for (int nt = 0; nt < 4; ++nt)
        bfr[nt] = *(const bf16x8*)&Bs[cur][(wc * 64 + nt * 16 + (lane & 15)) * 64 +
                                           kk * 32 + (lane >> 4) * 8];
#pragma unroll
      for (int mt = 0; mt < 4; ++mt)
#pragma unroll
        for (int nt = 0; nt < 4; ++nt)
          acc[mt][nt] = __builtin_amdgcn_mfma_f32_16x16x32_bf16(
              af[mt], bfr[nt], acc[mt][nt], 0, 0, 0);
    }
    asm volatile("s_waitcnt vmcnt(0)" ::: "memory");
    __syncthreads();
  }

#pragma unroll
  for (int nt = 0; nt < 4; ++nt) {
    const int col = n0 + wc * 64 + nt * 16 + (lane & 15);
    if (col >= N) continue;
    float badd = 0.f;
    if (bias1) badd += bias1[col];
    if (bias2 && col < bias2_limit) badd += bias2[col];
#pragma unroll
    for (int mt = 0; mt < 4; ++mt) {
      const int rbase = m0 + wr * 64 + mt * 16 + (lane >> 4) * 4;
#pragma unroll
      for (int r = 0; r < 4; ++r) {
        const int row = rbase + r;
        if (row < M) {
          float v = acc[mt][nt][r] + badd;
          if (OMODE == 0) {
            if (rowbias) v += rowbias[(int64_t)(row & 63) * ldc + col];
            ((float*)C)[(int64_t)row * ldc + col] = v;
          } else {
            const int cc = col & 255;
            const int jj = ((cc >> 5) << 4) + (cc & 15);
            ((short*)C)[(int64_t)row * 1024 + jj * 8 + ((cc >> 4) & 1) * 4 +
                        (col >> 8)] = f2bf(v);
          }
        }
      }
    }
  }
}

// ---------------------------------------------------------------------------
// GEMM 256x256 for the fc layer (short-K, WRITE-BOUND regime):
//  - single-buffered 64KB LDS K-loop -> 2 blocks/CU (launch_bounds(1024,8)):
//    one block's MFMA phase hides the other's epilogue writes.
//  - T2 XOR-swizzle on staged tiles (bank-conflict-free ds_read_b128).
//  - LDS-staged epilogue: acc -> LDS (64x256 f32 per mt-quadrant) -> fully
//    contiguous dwordx4 stores (1KB per wave-instruction) instead of scattered
//    single-dword stores in 64B segments at 40KB stride (the R12 1.5 TB/s
//    write ceiling). bias + rowbias become dwordx4 L2 loads.
//  - XCD-bijective block remap (A panel 1MB/XCD L2-resident, B reused 8x).
// ---------------------------------------------------------------------------
__global__ __launch_bounds__(1024, 8) void fpp_gemm256(
    const short* __restrict__ A, const short* __restrict__ B,
    float* __restrict__ C, const float* __restrict__ bias1,
    const float* __restrict__ rowbias,
    int M, int N, int K, int lda, int ldb, int ldc, int NT, int SUPER, int XCD) {
  int bid = blockIdx.x;
  if (XCD) {
    const int nx = gridDim.x >> 3;  // grid divisible by 8
    bid = (bid & 7) * nx + (bid >> 3);
  }
  const int per_super = SUPER * NT;
  const int srow = bid / per_super;
  const int rrem = bid - srow * per_super;
  const int mi = srow * SUPER + (rrem % SUPER);
  const int ni = rrem / SUPER;
  const int m0 = mi * 256, n0 = ni * 256;

  __shared__ __attribute__((aligned(16))) char smem[65536];  // 64 KB
  short* As = (short*)smem;            // 256x64 bf16 = 32 KB
  short* Bs = (short*)(smem + 32768);  // 32 KB
  float* st = (float*)smem;            // epilogue staging: 64x256 f32 = 64 KB

  const int tid = threadIdx.x;
  const int lane = tid & 63;
  const int wv = tid >> 6;          // 0..15
  const int wr = wv >> 2, wc = wv & 3;

  f32x4 acc[4][4];
#pragma unroll
  for (int a_ = 0; a_ < 4; ++a_)
#pragma unroll
    for (int b_ = 0; b_ < 4; ++b_) acc[a_][b_] = f32x4{0.f, 0.f, 0.f, 0.f};

  // stage with pre-swizzled global source (rule #21: LDS dest stays linear)
  auto stage = [&](int k0) {
#pragma unroll
    for (int c = 0; c < 2; ++c) {
      const int chunk = c * 1024 + tid;            // 16B slot id 0..2047
      const int row = chunk >> 3;                  // tile-local row 0..255
      const int kc8 = (chunk & 7) ^ (row & 7);     // inverse swizzle on source
      int gr = m0 + row; gr = (gr < M) ? gr : (M - 1);
      gload_lds16(A + (int64_t)gr * lda + k0 + kc8 * 8,
                  (char*)As + (c * 1024 + wv * 64) * 16);
    }
#pragma unroll
    for (int c = 0; c < 2; ++c) {
      const int chunk = c * 1024 + tid;
      const int row = chunk >> 3;
      const int kc8 = (chunk & 7) ^ (row & 7);
      int gn = n0 + row; gn = (gn < N) ? gn : (N - 1);
      gload_lds16(B + (int64_t)gn * ldb + k0 + kc8 * 8,
                  (char*)Bs + (c * 1024 + wv * 64) * 16);
    }
  };

  const int nk = K >> 6;
  for (int ks = 0; ks < nk; ++ks) {
    stage(ks << 6);
    __syncthreads();  // DMA landed (vmcnt0 before barrier) + visible to all
#pragma unroll
    for (int kk = 0; kk < 2; ++kk) {
      bf16x8 af[4], bfr[4];
#pragma unroll
      for (int mt = 0; mt < 4; ++mt) {
        const int row = wr * 64 + mt * 16 + (lane & 15);
        const int u = (kk * 4 + (lane >> 4)) ^ (row & 7);  // swizzled read
        af[mt] = *(const bf16x8*)&As[row * 64 + u * 8];
      }
#pragma unroll
      for (int nt = 0; nt < 4; ++nt) {
        const int row = wc * 64 + nt * 16 + (lane & 15);
        const int u = (kk * 4 + (lane >> 4)) ^ (row & 7);
        bfr[nt] = *(const bf16x8*)&Bs[row * 64 + u * 8];
      }
#pragma unroll
      for (int mt = 0; mt < 4; ++mt)
#pragma unroll
        for (int nt = 0; nt < 4; ++nt)
          acc[mt][nt] = __builtin_amdgcn_mfma_f32_16x16x32_bf16(
              af[mt], bfr[nt], acc[mt][nt], 0, 0, 0);
    }
    __syncthreads();  // all LDS reads done before next stage overwrites
  }

  // LDS-staged epilogue: per mt-quadrant, acc -> st[64][256] -> contiguous
  // dwordx4 stores (rows of 1KB). Global row for staged lrow:
  //   grow = m0 + (lrow>>4)*64 + mt*16 + (lrow&15)
#pragma unroll
  for (int mt = 0; mt < 4; ++mt) {
    if (mt) __syncthreads();  // previous quadrant's reads done
#pragma unroll
    for (int nt = 0; nt < 4; ++nt)
#pragma unroll
      for (int r = 0; r < 4; ++r)
        st[(wr * 16 + (lane >> 4) * 4 + r) * 256 + wc * 64 + nt * 16 +
           (lane & 15)] = acc[mt][nt][r];
    __syncthreads();
#pragma unroll
    for (int rr = 0; rr < 4; ++rr) {
      const int lrow = wv * 4 + rr;  // 0..63
      const int grow = m0 + ((lrow >> 4) << 6) + mt * 16 + (lrow & 15);
      const int col = n0 + (lane << 2);
      if (grow >= M) continue;
      f32x4 v = *(const f32x4*)&st[lrow * 256 + (lane << 2)];
      if (col + 3 < N) {
        if (bias1) {
          const f32x4 b = *(const f32x4*)&bias1[col];
          v += b;
        }
        if (rowbias) {
          const f32x4 u = *(const f32x4*)&rowbias[(int64_t)(grow & 63) * ldc + col];
          v += u;
        }
        *(f32x4*)&C[(int64_t)grow * ldc + col] = v;
      } else {
#pragma unroll
        for (int e = 0; e < 4; ++e) {
          const int ce = col + e;
          if (ce < N) {
            float vv = v[e];
            if (bias1) vv += bias1[ce];
            if (rowbias) vv += rowbias[(int64_t)(grow & 63) * ldc + ce];
            C[(int64_t)grow * ldc + ce] = vv;
          }
        }
      }
    }
  }
}

// ---------------------------------------------------------------------------
// GRU v2 (R10, passing): 8 blocks x 8 users x 8 waves. tp-split via shfl_xor;
// gi per-lane register prefetch; h double-buffered; one barrier per step.
// ---------------------------------------------------------------------------
__global__ __attribute__((amdgpu_waves_per_eu(2, 2))) __launch_bounds__(512)
void fpp_gru(
    const int* __restrict__ x, const float* __restrict__ h0,
    const short* __restrict__ WhhFrag, const float* __restrict__ b_hh,
    const short* __restrict__ giV, float* __restrict__ out,
    float* __restrict__ hlast) {
  __shared__ __attribute__((aligned(16))) short h_lds[2][16 * 264];  // 16.9 KB
  __shared__ __attribute__((aligned(16))) uint16_t x_lds[256 * 8];   // 4 KB

  const int tid = threadIdx.x;
  const int lane = tid & 63;
  const int wv = tid >> 6;  // wave 0..7
  const int u0 = blockIdx.x * 8;
  const int g = lane >> 4;
  const int lo = lane & 15;
  const int tp = (lane >= 32) ? 1 : 0;  // which 16-col half this lane gates
  const int uh = g & 1;                 // user-half selector: u = uh*4 + r

  for (int i = tid; i < 256 * 8; i += 512)
    x_lds[i] = (uint16_t)x[(i >> 3) * 64 + u0 + (i & 7)];
  // zero h rows 8-15 (both buffers): A-operand rows for nonexistent users
  for (int i = tid; i < 8 * 264; i += 512) {
    h_lds[0][8 * 264 + i] = 0;
    h_lds[1][8 * 264 + i] = 0;
  }

  // preload W_hh B-fragments: 48 coalesced dwordx4 loads (fragment-linear)
  bf16x8 Wf[6][8];
  {
    const bf16x8* wfp = (const bf16x8*)WhhFrag;
#pragma unroll
    for (int tt = 0; tt < 6; ++tt)
#pragma unroll
      for (int kc = 0; kc < 8; ++kc)
        Wf[tt][kc] = wfp[((wv * 6 + tt) * 8 + kc) * 64 + lane];
  }
  // n-gate b_hh for this lane's single column c = 32wv + tp*16 + lo
  const float bhh = b_hh[512 + 32 * wv + tp * 16 + lo];

  // 4 cells per lane: u = uh*4+r, c = 32wv + tp*16 + lo
  const int c_own = 32 * wv + tp * 16 + lo;
  float hreg[4];
#pragma unroll
  for (int r = 0; r < 4; ++r) {
    const int u = uh * 4 + r;
    const float v = h0[(u0 + u) * 256 + c_own];
    hreg[r] = v;
    h_lds[0][u * 264 + c_own] = f2bf(v);
  }

  // gi register prefetch: per lane, 4 x 8B (gates r,z,n for (u, c_own))
  typedef unsigned int uint2v __attribute__((ext_vector_type(2)));
  auto load_gi = [&](uint2v* dst, int ss) {
#pragma unroll
    for (int r = 0; r < 4; ++r) {
      const int u = uh * 4 + r;
      const int xid = x_lds[ss * 8 + u];
      dst[r] = *(const uint2v*)((const char*)giV + (int64_t)xid * 2048 +
                                (wv * 16 + lo) * 16 + tp * 8);
    }
  };

  __syncthreads();  // x_lds + h_lds[0] + zeroed rows visible

  uint2v gcur[4], gnx[4];
  load_gi(gcur, 0);

  for (int s = 0; s < 256; ++s) {
    load_gi(gnx, (s + 1) & 255);  // prefetch next step (wrapped tail: unused)

    const short* hr = h_lds[s & 1];
    short* hw = h_lds[(s + 1) & 1];

    // gh = h @ W_hh^T : 48 MFMAs; D rows 8-15 are zero (A rows zeroed)
    f32x4 acc[6];
#pragma unroll
    for (int tt = 0; tt < 6; ++tt) acc[tt] = f32x4{0.f, 0.f, 0.f, 0.f};
#pragma unroll
    for (int kc = 0; kc < 8; ++kc) {
      const bf16x8 a = *(const bf16x8*)&hr[lo * 264 + kc * 32 + g * 8];
#pragma unroll
      for (int tt = 0; tt < 6; ++tt)
        acc[tt] = __builtin_amdgcn_mfma_f32_16x16x32_bf16(a, Wf[tt][kc], acc[tt], 0, 0, 0);
    }

    // tp-split: odd tiles (tp=1) of lanes<32 -> lanes>=32 via shfl_xor(32).
    float mine[3][4];
#pragma unroll
    for (int G = 0; G < 3; ++G) {
#pragma unroll
      for (int r = 0; r < 4; ++r) {
        const float swv = __shfl_xor(acc[2 * G + 1][r], 32, 64);
        mine[G][r] = (lane < 32) ? acc[2 * G][r] : swv;
      }
    }

    // gates: 4 cells per lane
#pragma unroll
    for (int r = 0; r < 4; ++r) {
      const int u = uh * 4 + r;
      const short4 gv = *(const short4*)&gcur[r];
      const float gir = bf2f(gv.x);
      const float giz = bf2f(gv.y);
      const float gin = bf2f(gv.z);
      const float xr = mine[0][r] + gir;
      const float rr = __builtin_amdgcn_rcpf(1.f + __builtin_amdgcn_exp2f(-1.4426950408889634f * xr));
      const float xz = mine[1][r] + giz;
      const float zz = __builtin_amdgcn_rcpf(1.f + __builtin_amdgcn_exp2f(-1.4426950408889634f * xz));
      float xn = gin + rr * (mine[2][r] + bhh);
      xn = fminf(fmaxf(xn, -12.f), 12.f);
      const float E = __builtin_amdgcn_exp2f(2.8853900817779268f * xn);
      const float nn = (E - 1.f) * __builtin_amdgcn_rcpf(E + 1.f);
      const float hv = nn + zz * (hreg[r] - nn);
      hreg[r] = hv;
      hw[u * 264 + c_own] = f2bf(hv);
      out[((int64_t)s * 64 + u0 + u) * 256 + c_own] = hv;  // store not awaited
    }

    // single per-step barrier: h writes visible; vm ops stay in flight
    asm volatile("s_waitcnt lgkmcnt(0)\n\ts_barrier" ::: "memory");

#pragma unroll
    for (int r = 0; r < 4; ++r) gcur[r] = gnx[r];
  }

#pragma unroll
  for (int r = 0; r < 4; ++r) {
    const int u = uh * 4 + r;
    hlast[(u0 + u) * 256 + c_own] = hreg[r];
  }
}

// ---------------------------------------------------------------------------
// attention: per (u, i-block of 64): loop causal j-blocks; w in LDS; weighted
// sum of GRU hiddens; writes bf16 into A2 (stride 256). f32 vector math.
// ---------------------------------------------------------------------------
__global__ __launch_bounds__(256) void fpp_attn(
    const float* __restrict__ t_g, const float* __restrict__ s_g,
    const float* __restrict__ gout, short* __restrict__ A2) {
  const int u = blockIdx.x;   // 0..63
  const int ib = blockIdx.y;  // 0..3
  const int tid = threadIdx.x;
  const int iloc = tid >> 2;  // 0..63
  const int q = tid & 3;      // h quarter (64 each)

  __shared__ __attribute__((aligned(16))) float out_lds[64][272];  // q-seg stride 68
  __shared__ __attribute__((aligned(16))) float w_lds[64][65];
  __shared__ float ti[64], si0[64], si1[64], tj[64], sj0[64], sj1[64], sum_lds[64];

  if (tid < 64) {
    const int ig = ib * 64 + tid;
    ti[tid] = t_g[ig * 64 + u];
    si0[tid] = s_g[(ig * 64 + u) * 2 + 0];
    si1[tid] = s_g[(ig * 64 + u) * 2 + 1];
    sum_lds[tid] = 0.f;
  }

  f32x4 accv[16];
#pragma unroll
  for (int hh = 0; hh < 16; ++hh) accv[hh] = f32x4{0.f, 0.f, 0.f, 0.f};

  const int igl = ib * 64 + iloc;

  for (int jb = 0; jb <= ib; ++jb) {
    __syncthreads();  // protect LDS vs previous iteration readers
    {
      const int jj = tid >> 2;
      const float* src = gout + ((int64_t)(jb * 64 + jj) * 64 + u) * 256 + q * 64;
#pragma unroll
      for (int hh = 0; hh < 16; ++hh)
        *(f32x4*)&out_lds[jj][q * 68 + hh * 4] = *(const f32x4*)(src + hh * 4);
    }
    if (tid < 64) {
      const int jg = jb * 64 + tid;
      tj[tid] = t_g[jg * 64 + u];
      sj0[tid] = s_g[(jg * 64 + u) * 2 + 0];
      sj1[tid] = s_g[(jg * 64 + u) * 2 + 1];
    }
    __syncthreads();
    {
      const float tiv = ti[iloc], p0 = si0[iloc], p1 = si1[iloc];
#pragma unroll
      for (int jj = 0; jj < 16; ++jj) {
        const int j = q * 16 + jj;
        const int jgl = jb * 64 + j;
        const float dt = tiv - tj[j];
        // f_t = (cos(2*pi*dt)+1)*0.5*exp(-0.1*dt); v_cos takes revolutions
        const float ft = (__builtin_amdgcn_cosf(dt) + 1.f) * 0.5f *
                         __builtin_amdgcn_exp2f(-0.14426950408889634f * dt);
        const float dx = p0 - sj0[j], dy = p1 - sj1[j];
        const float ds = __builtin_amdgcn_sqrtf(dx * dx + dy * dy);
        const float fs = __builtin_amdgcn_exp2f(-144.26950408889634f * ds);
        float wvv = ft * fs + 1e-10f;
        if (jgl > igl) wvv = 0.f;  // causal
        w_lds[iloc][j] = wvv;
      }
    }
    __syncthreads();
    if (tid < 64) {
      float sm = 0.f;
#pragma unroll
      for (int j = 0; j < 64; ++j) sm += w_lds[tid][j];
      sum_lds[tid] += sm;
    }
    for (int j = 0; j < 64; ++j) {
      const float wvv = w_lds[iloc][j];
#pragma unroll
      for (int hh = 0; hh < 16; ++hh) {
        const f32x4 o = *(const f32x4*)&out_lds[j][q * 68 + hh * 4];
        accv[hh] += o * wvv;
      }
    }
  }
  __syncthreads();
  const float inv = 1.f / sum_lds[iloc];
  short* dst = A2 + (int64_t)((ib * 64 + iloc) * 64 + u) * 256 + q * 64;
#pragma unroll
  for (int hh = 0; hh < 16; ++hh) {
    const f32x4 v = accv[hh] * inv;
    short4 sv;
    sv.x = f2bf(v[0]); sv.y = f2bf(v[1]); sv.z = f2bf(v[2]); sv.w = f2bf(v[3]);
    *(short4*)(dst + hh * 4) = sv;
  }
}

// ---------------------------------------------------------------------------
extern "C" void kernel_launch(void* const* d_in, const int* in_sizes, int n_in,
                              void* d_out, int out_size, void* d_ws, size_t ws_size,
                              hipStream_t stream) {
  (void)in_sizes; (void)n_in; (void)out_size; (void)ws_size;
  const int*   x      = (const int*)  d_in[0];
  const float* t      = (const float*)d_in[1];
  const float* s      = (const float*)d_in[2];
  // d_in[3], d_in[4] (y_t, y_s) unused by reference
  const float* h0     = (const float*)d_in[5];
  const int*   au     = (const int*)  d_in[6];
  const float* enc_W  = (const float*)d_in[7];
  const float* user_W = (const float*)d_in[8];
  const float* W_ih   = (const float*)d_in[9];
  const float* W_hh   = (const float*)d_in[10];
  const float* b_ih   = (const float*)d_in[11];
  const float* b_hh   = (const float*)d_in[12];
  const float* fc_W   = (const float*)d_in[13];
  const float* fc_b   = (const float*)d_in[14];

  float* y = (float*)d_out;
  float* hlast = y + Y_ELEMS;

  char* ws = (char*)d_ws;
  short* giV   = (short*)(ws + 0);          // 10000x256x4 bf16, pair-packed
  short* A2    = (short*)(ws + 20480000);   // 16384x256 bf16 (attn out only)
  short* fcWb  = (short*)(ws + 28868608);   // 10000x512 bf16
  short* encWb = (short*)(ws + 39108608);   // 10000x256 bf16
  short* WihB  = (short*)(ws + 44228608);   // 768x256 bf16
  short* uWb   = (short*)(ws + 44621824);   // 64x256 bf16 (gathered p_u)
  float* U     = (float*)(ws + 44654592);   // 64x10000 f32 = p_u @ fc2^T
  float* gout  = (float*)(ws + 47214592);   // 256x64x256 f32 GRU hiddens
  // WhhFrag scratch lives inside d_out's y region (written by prep, read by
  // GRU, overwritten by the final GEMM).
  short* WhhFrag = (short*)(y + 80000000);  // 768x256 bf16, fragment-linear

  fpp_prep<<<1024, 256, 0, stream>>>(enc_W, W_ih, fc_W, user_W, W_hh, au,
                                     encWb, WihB, fcWb, uWb, WhhFrag);
  // giV = enc_W @ W_ih.T + b_ih (+ b_hh for n<512); bf16, pair-packed layout
  fpp_gemm_bt<2><<<79 * 6, 256, 0, stream>>>(
      encWb, WihB, giV, b_ih, b_hh, 512, nullptr,
      10000, 768, 256, 256, 256, 0, 79, 6, 1, 0);
  // U = p_u @ fc_W[:,256:].T  (64 x 10000, f32; no bias)
  fpp_gemm_bt<0><<<79, 256, 0, stream>>>(
      uWb, fcWb + 256, U, nullptr, nullptr, 0, nullptr,
      64, 10000, 256, 256, 512, 10000, 1, 79, 1, 0);
  fpp_gru<<<8, 512, 0, stream>>>(x, h0, WhhFrag, b_hh, giV, gout, hlast);
  fpp_attn<<<dim3(64, 4), 256, 0, stream>>>(t, s, gout, A2);
  // y = attn @ fc_W[:,:256].T + fc_b + U[row&63]  (256^2-tile GEMM)
  fpp_gemm256<<<64 * 40, 1024, 0, stream>>>(
      A2, fcWb, y, fc_b, U,
      16384, 10000, 256, 256, 512, 10000, 40, 8, 1);
}

// Round 14
// 862.685 us; speedup vs baseline: 2.1158x; 2.1158x over previous
//
#include <hip/hip_runtime.h>
#include <stdint.h>

// FlashbackPlusPlus: embed->GRU->spatiotemporal causal attention->FC
// S=256 U=64 H=256 V=10000
#define S_LEN 256
#define U_LEN 64
#define H_DIM 256
#define V_DIM 10000
#define Y_ELEMS 163840000LL  // S*U*V

typedef short bf16x8 __attribute__((ext_vector_type(8)));
typedef float f32x4 __attribute__((ext_vector_type(4)));

__device__ __forceinline__ short f2bf(float f) {
  union { float f; uint32_t u; } v; v.f = f;
  uint32_t r = v.u + 0x7FFFu + ((v.u >> 16) & 1u);  // RNE
  return (short)(r >> 16);
}
__device__ __forceinline__ float bf2f(short s) {
  union { uint32_t u; float f; } v; v.u = ((uint32_t)(uint16_t)s) << 16;
  return v.f;
}

// global -> LDS async copy, 16B per lane. LDS dest = wave-uniform base + lane*16.
__device__ __forceinline__ void gload_lds16(const void* g, void* l) {
  __builtin_amdgcn_global_load_lds(
      (const __attribute__((address_space(1))) char*)(uintptr_t)g,
      (__attribute__((address_space(3))) char*)(uintptr_t)l, 16, 0, 0);
}

// ---------------------------------------------------------------------------
// prep: f32->bf16 weight conversions + active-user embedding gather + W_hh
// fragment pack (fragment-linear so the GRU preamble is coalesced dwordx4).
// ---------------------------------------------------------------------------
__global__ __launch_bounds__(256) void fpp_prep(
    const float* __restrict__ enc_W, const float* __restrict__ W_ih,
    const float* __restrict__ fc_W, const float* __restrict__ user_W,
    const float* __restrict__ W_hh, const int* __restrict__ active_user,
    short* __restrict__ encWb, short* __restrict__ WihB,
    short* __restrict__ fcWb, short* __restrict__ uWb,
    short* __restrict__ WhhFrag) {
  const int tid = blockIdx.x * 256 + threadIdx.x;
  const int stride = gridDim.x * 256;
  for (int i = tid; i < V_DIM * H_DIM; i += stride) encWb[i] = f2bf(enc_W[i]);
  for (int i = tid; i < 3 * H_DIM * H_DIM; i += stride) WihB[i] = f2bf(W_ih[i]);
  for (int i = tid; i < V_DIM * 2 * H_DIM; i += stride) fcWb[i] = f2bf(fc_W[i]);
  // uWb[u][k] = user_W[active_user[u]][k]  (64 x 256 bf16)
  for (int i = tid; i < 64 * 256; i += stride) {
    const int u = i >> 8, k = i & 255;
    uWb[i] = f2bf(user_W[(int64_t)active_user[u] * 256 + k]);
  }
  // WhhFrag[i], i = (((wv*6+tt)*8+kc)*64+lane)*8+j ; holds W_hh[n][k] bf16 with
  // n = (tt>>1)*256 + 32*wv + (tt&1)*16 + (lane&15), k = kc*32 + (lane>>4)*8 + j
  for (int i = tid; i < 768 * 256; i += stride) {
    const int j = i & 7, ln = (i >> 3) & 63, kc = (i >> 9) & 7, t12 = i >> 12;
    const int tt = t12 % 6, wvv = t12 / 6;
    const int n = (tt >> 1) * 256 + 32 * wvv + (tt & 1) * 16 + (ln & 15);
    const int k = kc * 32 + (ln >> 4) * 8 + j;
    WhhFrag[i] = f2bf(W_hh[n * 256 + k]);
  }
}

// ---------------------------------------------------------------------------
// GEMM 128x128 (R11, passing) -- used for gemm1 (gi pair-packed) and gemm_u.
// OMODE: 0 = f32 linear, 2 = bf16 gi pair-packed
// ---------------------------------------------------------------------------
template <int OMODE>
__global__ __launch_bounds__(256) void fpp_gemm_bt(
    const short* __restrict__ A, const short* __restrict__ B, void* __restrict__ C,
    const float* __restrict__ bias1, const float* __restrict__ bias2, int bias2_limit,
    const float* __restrict__ rowbias,
    int M, int N, int K, int lda, int ldb, int ldc,
    int MT, int NT, int SUPER, int XCD) {
  int bid = blockIdx.x;
  if (XCD) {
    const int nx = gridDim.x >> 3;
    bid = (bid & 7) * nx + (bid >> 3);
  }
  const int per_super = SUPER * NT;
  const int srow = bid / per_super;
  const int rrem = bid - srow * per_super;
  const int mi = srow * SUPER + (rrem % SUPER);
  const int ni = rrem / SUPER;
  const int m0 = mi * 128, n0 = ni * 128;

  __shared__ __attribute__((aligned(16))) short As[2][128 * 64];
  __shared__ __attribute__((aligned(16))) short Bs[2][128 * 64];

  const int tid = threadIdx.x;
  const int lane = tid & 63;
  const int wv = tid >> 6;
  const int wr = wv >> 1, wc = wv & 1;

  f32x4 acc[4][4];
#pragma unroll
  for (int a_ = 0; a_ < 4; ++a_)
#pragma unroll
    for (int b_ = 0; b_ < 4; ++b_) acc[a_][b_] = f32x4{0.f, 0.f, 0.f, 0.f};

  auto stage = [&](int buf, int k0) {
#pragma unroll
    for (int c = 0; c < 4; ++c) {
      const int chunk = c * 256 + tid;
      const int row = chunk >> 3, kc8 = chunk & 7;
      int gr = m0 + row; gr = (gr < M) ? gr : (M - 1);
      gload_lds16(A + (int64_t)gr * lda + k0 + kc8 * 8,
                  (char*)&As[buf][0] + (c * 256 + wv * 64) * 16);
    }
#pragma unroll
    for (int c = 0; c < 4; ++c) {
      const int chunk = c * 256 + tid;
      const int row = chunk >> 3, kc8 = chunk & 7;
      int gn = n0 + row; gn = (gn < N) ? gn : (N - 1);
      gload_lds16(B + (int64_t)gn * ldb + k0 + kc8 * 8,
                  (char*)&Bs[buf][0] + (c * 256 + wv * 64) * 16);
    }
  };

  const int nk = K >> 6;
  stage(0, 0);
  asm volatile("s_waitcnt vmcnt(0)" ::: "memory");
  __syncthreads();
  for (int ks = 0; ks < nk; ++ks) {
    const int cur = ks & 1;
    if (ks + 1 < nk) stage(cur ^ 1, (ks + 1) << 6);
#pragma unroll
    for (int kk = 0; kk < 2; ++kk) {
      bf16x8 af[4], bfr[4];
#pragma unroll
      for (int mt = 0; mt < 4; ++mt)
        af[mt] = *(const bf16x8*)&As[cur][(wr * 64 + mt * 16 + (lane & 15)) * 64 +
                                          kk * 32 + (lane >> 4) * 8];
#pragma unroll
      for (int nt = 0; nt < 4; ++nt)
        bfr[nt] = *(const bf16x8*)&Bs[cur][(wc * 64 + nt * 16 + (lane & 15)) * 64 +
                                           kk * 32 + (lane >> 4) * 8];
#pragma unroll
      for (int mt = 0; mt < 4; ++mt)
#pragma unroll
        for (int nt = 0; nt < 4; ++nt)
          acc[mt][nt] = __builtin_amdgcn_mfma_f32_16x16x32_bf16(
              af[mt], bfr[nt], acc[mt][nt], 0, 0, 0);
    }
    asm volatile("s_waitcnt vmcnt(0)" ::: "memory");
    __syncthreads();
  }

#pragma unroll
  for (int nt = 0; nt < 4; ++nt) {
    const int col = n0 + wc * 64 + nt * 16 + (lane & 15);
    if (col >= N) continue;
    float badd = 0.f;
    if (bias1) badd += bias1[col];
    if (bias2 && col < bias2_limit) badd += bias2[col];
#pragma unroll
    for (int mt = 0; mt < 4; ++mt) {
      const int rbase = m0 + wr * 64 + mt * 16 + (lane >> 4) * 4;
#pragma unroll
      for (int r = 0; r < 4; ++r) {
        const int row = rbase + r;
        if (row < M) {
          float v = acc[mt][nt][r] + badd;
          if (OMODE == 0) {
            if (rowbias) v += rowbias[(int64_t)(row & 63) * ldc + col];
            ((float*)C)[(int64_t)row * ldc + col] = v;
          } else {
            const int cc = col & 255;
            const int jj = ((cc >> 5) << 4) + (cc & 15);
            ((short*)C)[(int64_t)row * 1024 + jj * 8 + ((cc >> 4) & 1) * 4 +
                        (col >> 8)] = f2bf(v);
          }
        }
      }
    }
  }
}

// ---------------------------------------------------------------------------
// GEMM 256x256 for the fc layer (short-K, WRITE-BOUND regime).
//  - R12's double-buffered K-loop (128KB LDS, plain launch_bounds(1024):
//    4 waves/SIMD -> 128-VGPR budget; NO min-waves hint -- R13's (1024,8)
//    capped VGPR at 64 and spilled acc -> 6GB scratch traffic).
//  - T2 XOR-swizzle on staged tiles (bank-conflict-free ds_read_b128).
//  - R13's LDS-staged epilogue (proven correct): acc -> st (stride 260:
//    2-way write aliasing = free) -> contiguous 1KB-per-instruction dwordx4
//    stores (full-line writes; the old scattered 64B@40KB-stride pattern
//    capped at ~1.5 TB/s). st reuses the staging LDS (dead after K-loop).
//  - XCD-bijective block remap (A panel 1MB/XCD L2-resident, B reused 8x).
// ---------------------------------------------------------------------------
#define STSTRIDE 260
__global__ __launch_bounds__(1024) void fpp_gemm256(
    const short* __restrict__ A, const short* __restrict__ B,
    float* __restrict__ C, const float* __restrict__ bias1,
    const float* __restrict__ rowbias,
    int M, int N, int K, int lda, int ldb, int ldc, int NT, int SUPER, int XCD) {
  int bid = blockIdx.x;
  if (XCD) {
    const int nx = gridDim.x >> 3;  // grid divisible by 8
    bid = (bid & 7) * nx + (bid >> 3);
  }
  const int per_super = SUPER * NT;
  const int srow = bid / per_super;
  const int rrem = bid - srow * per_super;
  const int mi = srow * SUPER + (rrem % SUPER);
  const int ni = rrem / SUPER;
  const int m0 = mi * 256, n0 = ni * 256;

  __shared__ __attribute__((aligned(16))) char smem[131072];  // 128 KB
  float* st = (float*)smem;  // epilogue staging 64 x STSTRIDE f32 (66.6 KB)

  const int tid = threadIdx.x;
  const int lane = tid & 63;
  const int wv = tid >> 6;          // 0..15
  const int wr = wv >> 2, wc = wv & 3;

  f32x4 acc[4][4];
#pragma unroll
  for (int a_ = 0; a_ < 4; ++a_)
#pragma unroll
    for (int b_ = 0; b_ < 4; ++b_) acc[a_][b_] = f32x4{0.f, 0.f, 0.f, 0.f};

  // stage with pre-swizzled global source (rule #21: LDS dest stays linear)
  auto stage = [&](int buf, int k0) {
    char* Ad = smem + buf * 32768;
    char* Bd = smem + 65536 + buf * 32768;
#pragma unroll
    for (int c = 0; c < 2; ++c) {
      const int chunk = c * 1024 + tid;            // 16B slot id 0..2047
      const int row = chunk >> 3;                  // tile-local row 0..255
      const int kc8 = (chunk & 7) ^ (row & 7);     // inverse swizzle on source
      int gr = m0 + row; gr = (gr < M) ? gr : (M - 1);
      gload_lds16(A + (int64_t)gr * lda + k0 + kc8 * 8,
                  Ad + (c * 1024 + wv * 64) * 16);
    }
#pragma unroll
    for (int c = 0; c < 2; ++c) {
      const int chunk = c * 1024 + tid;
      const int row = chunk >> 3;
      const int kc8 = (chunk & 7) ^ (row & 7);
      int gn = n0 + row; gn = (gn < N) ? gn : (N - 1);
      gload_lds16(B + (int64_t)gn * ldb + k0 + kc8 * 8,
                  Bd + (c * 1024 + wv * 64) * 16);
    }
  };

  const int nk = K >> 6;
  stage(0, 0);
  asm volatile("s_waitcnt vmcnt(0)" ::: "memory");
  __syncthreads();
  for (int ks = 0; ks < nk; ++ks) {
    const int cur = ks & 1;
    if (ks + 1 < nk) stage(cur ^ 1, (ks + 1) << 6);  // async prefetch
    const short* Asb = (const short*)(smem + cur * 32768);
    const short* Bsb = (const short*)(smem + 65536 + cur * 32768);
#pragma unroll
    for (int kk = 0; kk < 2; ++kk) {
      bf16x8 af[4], bfr[4];
#pragma unroll
      for (int mt = 0; mt < 4; ++mt) {
        const int row = wr * 64 + mt * 16 + (lane & 15);
        const int u = (kk * 4 + (lane >> 4)) ^ (row & 7);  // swizzled read
        af[mt] = *(const bf16x8*)&Asb[row * 64 + u * 8];
      }
#pragma unroll
      for (int nt = 0; nt < 4; ++nt) {
        const int row = wc * 64 + nt * 16 + (lane & 15);
        const int u = (kk * 4 + (lane >> 4)) ^ (row & 7);
        bfr[nt] = *(const bf16x8*)&Bsb[row * 64 + u * 8];
      }
#pragma unroll
      for (int mt = 0; mt < 4; ++mt)
#pragma unroll
        for (int nt = 0; nt < 4; ++nt)
          acc[mt][nt] = __builtin_amdgcn_mfma_f32_16x16x32_bf16(
              af[mt], bfr[nt], acc[mt][nt], 0, 0, 0);
    }
    asm volatile("s_waitcnt vmcnt(0)" ::: "memory");
    __syncthreads();
  }

  // LDS-staged epilogue (R13, proven): per mt-quadrant, acc -> st[64][260]
  // -> contiguous dwordx4 stores (each wave stores full 1KB rows).
  //   grow = m0 + (lrow>>4)*64 + mt*16 + (lrow&15)
#pragma unroll
  for (int mt = 0; mt < 4; ++mt) {
    if (mt) __syncthreads();  // previous quadrant's reads done
#pragma unroll
    for (int nt = 0; nt < 4; ++nt)
#pragma unroll
      for (int r = 0; r < 4; ++r)
        st[(wr * 16 + (lane >> 4) * 4 + r) * STSTRIDE + wc * 64 + nt * 16 +
           (lane & 15)] = acc[mt][nt][r];
    __syncthreads();
#pragma unroll
    for (int rr = 0; rr < 4; ++rr) {
      const int lrow = wv * 4 + rr;  // 0..63
      const int grow = m0 + ((lrow >> 4) << 6) + mt * 16 + (lrow & 15);
      const int col = n0 + (lane << 2);
      if (grow >= M) continue;
      f32x4 v = *(const f32x4*)&st[lrow * STSTRIDE + (lane << 2)];
      if (col + 3 < N) {
        if (bias1) {
          const f32x4 b = *(const f32x4*)&bias1[col];
          v += b;
        }
        if (rowbias) {
          const f32x4 u = *(const f32x4*)&rowbias[(int64_t)(grow & 63) * ldc + col];
          v += u;
        }
        *(f32x4*)&C[(int64_t)grow * ldc + col] = v;
      } else {
#pragma unroll
        for (int e = 0; e < 4; ++e) {
          const int ce = col + e;
          if (ce < N) {
            float vv = v[e];
            if (bias1) vv += bias1[ce];
            if (rowbias) vv += rowbias[(int64_t)(grow & 63) * ldc + ce];
            C[(int64_t)grow * ldc + ce] = vv;
          }
        }
      }
    }
  }
}

// ---------------------------------------------------------------------------
// GRU v2 (R10, passing): 8 blocks x 8 users x 8 waves. tp-split via shfl_xor;
// gi per-lane register prefetch; h double-buffered; one barrier per step.
// ---------------------------------------------------------------------------
__global__ __attribute__((amdgpu_waves_per_eu(2, 2))) __launch_bounds__(512)
void fpp_gru(
    const int* __restrict__ x, const float* __restrict__ h0,
    const short* __restrict__ WhhFrag, const float* __restrict__ b_hh,
    const short* __restrict__ giV, float* __restrict__ out,
    float* __restrict__ hlast) {
  __shared__ __attribute__((aligned(16))) short h_lds[2][16 * 264];  // 16.9 KB
  __shared__ __attribute__((aligned(16))) uint16_t x_lds[256 * 8];   // 4 KB

  const int tid = threadIdx.x;
  const int lane = tid & 63;
  const int wv = tid >> 6;  // wave 0..7
  const int u0 = blockIdx.x * 8;
  const int g = lane >> 4;
  const int lo = lane & 15;
  const int tp = (lane >= 32) ? 1 : 0;  // which 16-col half this lane gates
  const int uh = g & 1;                 // user-half selector: u = uh*4 + r

  for (int i = tid; i < 256 * 8; i += 512)
    x_lds[i] = (uint16_t)x[(i >> 3) * 64 + u0 + (i & 7)];
  // zero h rows 8-15 (both buffers): A-operand rows for nonexistent users
  for (int i = tid; i < 8 * 264; i += 512) {
    h_lds[0][8 * 264 + i] = 0;
    h_lds[1][8 * 264 + i] = 0;
  }

  // preload W_hh B-fragments: 48 coalesced dwordx4 loads (fragment-linear)
  bf16x8 Wf[6][8];
  {
    const bf16x8* wfp = (const bf16x8*)WhhFrag;
#pragma unroll
    for (int tt = 0; tt < 6; ++tt)
#pragma unroll
      for (int kc = 0; kc < 8; ++kc)
        Wf[tt][kc] = wfp[((wv * 6 + tt) * 8 + kc) * 64 + lane];
  }
  // n-gate b_hh for this lane's single column c = 32wv + tp*16 + lo
  const float bhh = b_hh[512 + 32 * wv + tp * 16 + lo];

  // 4 cells per lane: u = uh*4+r, c = 32wv + tp*16 + lo
  const int c_own = 32 * wv + tp * 16 + lo;
  float hreg[4];
#pragma unroll
  for (int r = 0; r < 4; ++r) {
    const int u = uh * 4 + r;
    const float v = h0[(u0 + u) * 256 + c_own];
    hreg[r] = v;
    h_lds[0][u * 264 + c_own] = f2bf(v);
  }

  // gi register prefetch: per lane, 4 x 8B (gates r,z,n for (u, c_own))
  typedef unsigned int uint2v __attribute__((ext_vector_type(2)));
  auto load_gi = [&](uint2v* dst, int ss) {
#pragma unroll
    for (int r = 0; r < 4; ++r) {
      const int u = uh * 4 + r;
      const int xid = x_lds[ss * 8 + u];
      dst[r] = *(const uint2v*)((const char*)giV + (int64_t)xid * 2048 +
                                (wv * 16 + lo) * 16 + tp * 8);
    }
  };

  __syncthreads();  // x_lds + h_lds[0] + zeroed rows visible

  uint2v gcur[4], gnx[4];
  load_gi(gcur, 0);

  for (int s = 0; s < 256; ++s) {
    load_gi(gnx, (s + 1) & 255);  // prefetch next step (wrapped tail: unused)

    const short* hr = h_lds[s & 1];
    short* hw = h_lds[(s + 1) & 1];

    // gh = h @ W_hh^T : 48 MFMAs; D rows 8-15 are zero (A rows zeroed)
    f32x4 acc[6];
#pragma unroll
    for (int tt = 0; tt < 6; ++tt) acc[tt] = f32x4{0.f, 0.f, 0.f, 0.f};
#pragma unroll
    for (int kc = 0; kc < 8; ++kc) {
      const bf16x8 a = *(const bf16x8*)&hr[lo * 264 + kc * 32 + g * 8];
#pragma unroll
      for (int tt = 0; tt < 6; ++tt)
        acc[tt] = __builtin_amdgcn_mfma_f32_16x16x32_bf16(a, Wf[tt][kc], acc[tt], 0, 0, 0);
    }

    // tp-split: odd tiles (tp=1) of lanes<32 -> lanes>=32 via shfl_xor(32).
    float mine[3][4];
#pragma unroll
    for (int G = 0; G < 3; ++G) {
#pragma unroll
      for (int r = 0; r < 4; ++r) {
        const float swv = __shfl_xor(acc[2 * G + 1][r], 32, 64);
        mine[G][r] = (lane < 32) ? acc[2 * G][r] : swv;
      }
    }

    // gates: 4 cells per lane
#pragma unroll
    for (int r = 0; r < 4; ++r) {
      const int u = uh * 4 + r;
      const short4 gv = *(const short4*)&gcur[r];
      const float gir = bf2f(gv.x);
      const float giz = bf2f(gv.y);
      const float gin = bf2f(gv.z);
      const float xr = mine[0][r] + gir;
      const float rr = __builtin_amdgcn_rcpf(1.f + __builtin_amdgcn_exp2f(-1.4426950408889634f * xr));
      const float xz = mine[1][r] + giz;
      const float zz = __builtin_amdgcn_rcpf(1.f + __builtin_amdgcn_exp2f(-1.4426950408889634f * xz));
      float xn = gin + rr * (mine[2][r] + bhh);
      xn = fminf(fmaxf(xn, -12.f), 12.f);
      const float E = __builtin_amdgcn_exp2f(2.8853900817779268f * xn);
      const float nn = (E - 1.f) * __builtin_amdgcn_rcpf(E + 1.f);
      const float hv = nn + zz * (hreg[r] - nn);
      hreg[r] = hv;
      hw[u * 264 + c_own] = f2bf(hv);
      out[((int64_t)s * 64 + u0 + u) * 256 + c_own] = hv;  // store not awaited
    }

    // single per-step barrier: h writes visible; vm ops stay in flight
    asm volatile("s_waitcnt lgkmcnt(0)\n\ts_barrier" ::: "memory");

#pragma unroll
    for (int r = 0; r < 4; ++r) gcur[r] = gnx[r];
  }

#pragma unroll
  for (int r = 0; r < 4; ++r) {
    const int u = uh * 4 + r;
    hlast[(u0 + u) * 256 + c_own] = hreg[r];
  }
}

// ---------------------------------------------------------------------------
// attention: per (u, i-block of 64): loop causal j-blocks; w in LDS; weighted
// sum of GRU hiddens; writes bf16 into A2 (stride 256). f32 vector math.
// ---------------------------------------------------------------------------
__global__ __launch_bounds__(256) void fpp_attn(
    const float* __restrict__ t_g, const float* __restrict__ s_g,
    const float* __restrict__ gout, short* __restrict__ A2) {
  const int u = blockIdx.x;   // 0..63
  const int ib = blockIdx.y;  // 0..3
  const int tid = threadIdx.x;
  const int iloc = tid >> 2;  // 0..63
  const int q = tid & 3;      // h quarter (64 each)

  __shared__ __attribute__((aligned(16))) float out_lds[64][272];  // q-seg stride 68
  __shared__ __attribute__((aligned(16))) float w_lds[64][65];
  __shared__ float ti[64], si0[64], si1[64], tj[64], sj0[64], sj1[64], sum_lds[64];

  if (tid < 64) {
    const int ig = ib * 64 + tid;
    ti[tid] = t_g[ig * 64 + u];
    si0[tid] = s_g[(ig * 64 + u) * 2 + 0];
    si1[tid] = s_g[(ig * 64 + u) * 2 + 1];
    sum_lds[tid] = 0.f;
  }

  f32x4 accv[16];
#pragma unroll
  for (int hh = 0; hh < 16; ++hh) accv[hh] = f32x4{0.f, 0.f, 0.f, 0.f};

  const int igl = ib * 64 + iloc;

  for (int jb = 0; jb <= ib; ++jb) {
    __syncthreads();  // protect LDS vs previous iteration readers
    {
      const int jj = tid >> 2;
      const float* src = gout + ((int64_t)(jb * 64 + jj) * 64 + u) * 256 + q * 64;
#pragma unroll
      for (int hh = 0; hh < 16; ++hh)
        *(f32x4*)&out_lds[jj][q * 68 + hh * 4] = *(const f32x4*)(src + hh * 4);
    }
    if (tid < 64) {
      const int jg = jb * 64 + tid;
      tj[tid] = t_g[jg * 64 + u];
      sj0[tid] = s_g[(jg * 64 + u) * 2 + 0];
      sj1[tid] = s_g[(jg * 64 + u) * 2 + 1];
    }
    __syncthreads();
    {
      const float tiv = ti[iloc], p0 = si0[iloc], p1 = si1[iloc];
#pragma unroll
      for (int jj = 0; jj < 16; ++jj) {
        const int j = q * 16 + jj;
        const int jgl = jb * 64 + j;
        const float dt = tiv - tj[j];
        // f_t = (cos(2*pi*dt)+1)*0.5*exp(-0.1*dt); v_cos takes revolutions
        const float ft = (__builtin_amdgcn_cosf(dt) + 1.f) * 0.5f *
                         __builtin_amdgcn_exp2f(-0.14426950408889634f * dt);
        const float dx = p0 - sj0[j], dy = p1 - sj1[j];
        const float ds = __builtin_amdgcn_sqrtf(dx * dx + dy * dy);
        const float fs = __builtin_amdgcn_exp2f(-144.26950408889634f * ds);
        float wvv = ft * fs + 1e-10f;
        if (jgl > igl) wvv = 0.f;  // causal
        w_lds[iloc][j] = wvv;
      }
    }
    __syncthreads();
    if (tid < 64) {
      float sm = 0.f;
#pragma unroll
      for (int j = 0; j < 64; ++j) sm += w_lds[tid][j];
      sum_lds[tid] += sm;
    }
    for (int j = 0; j < 64; ++j) {
      const float wvv = w_lds[iloc][j];
#pragma unroll
      for (int hh = 0; hh < 16; ++hh) {
        const f32x4 o = *(const f32x4*)&out_lds[j][q * 68 + hh * 4];
        accv[hh] += o * wvv;
      }
    }
  }
  __syncthreads();
  const float inv = 1.f / sum_lds[iloc];
  short* dst = A2 + (int64_t)((ib * 64 + iloc) * 64 + u) * 256 + q * 64;
#pragma unroll
  for (int hh = 0; hh < 16; ++hh) {
    const f32x4 v = accv[hh] * inv;
    short4 sv;
    sv.x = f2bf(v[0]); sv.y = f2bf(v[1]); sv.z = f2bf(v[2]); sv.w = f2bf(v[3]);
    *(short4*)(dst + hh * 4) = sv;
  }
}

// ---------------------------------------------------------------------------
extern "C" void kernel_launch(void* const* d_in, const int* in_sizes, int n_in,
                              void* d_out, int out_size, void* d_ws, size_t ws_size,
                              hipStream_t stream) {
  (void)in_sizes; (void)n_in; (void)out_size; (void)ws_size;
  const int*   x      = (const int*)  d_in[0];
  const float* t      = (const float*)d_in[1];
  const float* s      = (const float*)d_in[2];
  // d_in[3], d_in[4] (y_t, y_s) unused by reference
  const float* h0     = (const float*)d_in[5];
  const int*   au     = (const int*)  d_in[6];
  const float* enc_W  = (const float*)d_in[7];
  const float* user_W = (const float*)d_in[8];
  const float* W_ih   = (const float*)d_in[9];
  const float* W_hh   = (const float*)d_in[10];
  const float* b_ih   = (const float*)d_in[11];
  const float* b_hh   = (const float*)d_in[12];
  const float* fc_W   = (const float*)d_in[13];
  const float* fc_b   = (const float*)d_in[14];

  float* y = (float*)d_out;
  float* hlast = y + Y_ELEMS;

  char* ws = (char*)d_ws;
  short* giV   = (short*)(ws + 0);          // 10000x256x4 bf16, pair-packed
  short* A2    = (short*)(ws + 20480000);   // 16384x256 bf16 (attn out only)
  short* fcWb  = (short*)(ws + 28868608);   // 10000x512 bf16
  short* encWb = (short*)(ws + 39108608);   // 10000x256 bf16
  short* WihB  = (short*)(ws + 44228608);   // 768x256 bf16
  short* uWb   = (short*)(ws + 44621824);   // 64x256 bf16 (gathered p_u)
  float* U     = (float*)(ws + 44654592);   // 64x10000 f32 = p_u @ fc2^T
  float* gout  = (float*)(ws + 47214592);   // 256x64x256 f32 GRU hiddens
  // WhhFrag scratch lives inside d_out's y region (written by prep, read by
  // GRU, overwritten by the final GEMM).
  short* WhhFrag = (short*)(y + 80000000);  // 768x256 bf16, fragment-linear

  fpp_prep<<<1024, 256, 0, stream>>>(enc_W, W_ih, fc_W, user_W, W_hh, au,
                                     encWb, WihB, fcWb, uWb, WhhFrag);
  // giV = enc_W @ W_ih.T + b_ih (+ b_hh for n<512); bf16, pair-packed layout
  fpp_gemm_bt<2><<<79 * 6, 256, 0, stream>>>(
      encWb, WihB, giV, b_ih, b_hh, 512, nullptr,
      10000, 768, 256, 256, 256, 0, 79, 6, 1, 0);
  // U = p_u @ fc_W[:,256:].T  (64 x 10000, f32; no bias)
  fpp_gemm_bt<0><<<79, 256, 0, stream>>>(
      uWb, fcWb + 256, U, nullptr, nullptr, 0, nullptr,
      64, 10000, 256, 256, 512, 10000, 1, 79, 1, 0);
  fpp_gru<<<8, 512, 0, stream>>>(x, h0, WhhFrag, b_hh, giV, gout, hlast);
  fpp_attn<<<dim3(64, 4), 256, 0, stream>>>(t, s, gout, A2);
  // y = attn @ fc_W[:,:256].T + fc_b + U[row&63]  (256^2-tile GEMM)
  fpp_gemm256<<<64 * 40, 1024, 0, stream>>>(
      A2, fcWb, y, fc_b, U,
      16384, 10000, 256, 256, 512, 10000, 40, 8, 1);
}

// Round 15
// 802.542 us; speedup vs baseline: 2.2743x; 1.0749x over previous
//
#include <hip/hip_runtime.h>
#include <stdint.h>

// FlashbackPlusPlus: embed->GRU->spatiotemporal causal attention->FC
// S=256 U=64 H=256 V=10000
#define S_LEN 256
#define U_LEN 64
#define H_DIM 256
#define V_DIM 10000
#define Y_ELEMS 163840000LL  // S*U*V

typedef short bf16x8 __attribute__((ext_vector_type(8)));
typedef float f32x4 __attribute__((ext_vector_type(4)));

__device__ __forceinline__ short f2bf(float f) {
  union { float f; uint32_t u; } v; v.f = f;
  uint32_t r = v.u + 0x7FFFu + ((v.u >> 16) & 1u);  // RNE
  return (short)(r >> 16);
}
__device__ __forceinline__ float bf2f(short s) {
  union { uint32_t u; float f; } v; v.u = ((uint32_t)(uint16_t)s) << 16;
  return v.f;
}

// global -> LDS async copy, 16B per lane. LDS dest = wave-uniform base + lane*16.
__device__ __forceinline__ void gload_lds16(const void* g, void* l) {
  __builtin_amdgcn_global_load_lds(
      (const __attribute__((address_space(1))) char*)(uintptr_t)g,
      (__attribute__((address_space(3))) char*)(uintptr_t)l, 16, 0, 0);
}

// ---------------------------------------------------------------------------
// prep: f32->bf16 weight conversions + active-user embedding gather + W_hh
// fragment pack (fragment-linear so the GRU preamble is coalesced dwordx4).
// ---------------------------------------------------------------------------
__global__ __launch_bounds__(256) void fpp_prep(
    const float* __restrict__ enc_W, const float* __restrict__ W_ih,
    const float* __restrict__ fc_W, const float* __restrict__ user_W,
    const float* __restrict__ W_hh, const int* __restrict__ active_user,
    short* __restrict__ encWb, short* __restrict__ WihB,
    short* __restrict__ fcWb, short* __restrict__ uWb,
    short* __restrict__ WhhFrag) {
  const int tid = blockIdx.x * 256 + threadIdx.x;
  const int stride = gridDim.x * 256;
  for (int i = tid; i < V_DIM * H_DIM; i += stride) encWb[i] = f2bf(enc_W[i]);
  for (int i = tid; i < 3 * H_DIM * H_DIM; i += stride) WihB[i] = f2bf(W_ih[i]);
  for (int i = tid; i < V_DIM * 2 * H_DIM; i += stride) fcWb[i] = f2bf(fc_W[i]);
  // uWb[u][k] = user_W[active_user[u]][k]  (64 x 256 bf16)
  for (int i = tid; i < 64 * 256; i += stride) {
    const int u = i >> 8, k = i & 255;
    uWb[i] = f2bf(user_W[(int64_t)active_user[u] * 256 + k]);
  }
  // WhhFrag[i], i = (((wv*6+tt)*8+kc)*64+lane)*8+j ; holds W_hh[n][k] bf16 with
  // n = (tt>>1)*256 + 32*wv + (tt&1)*16 + (lane&15), k = kc*32 + (lane>>4)*8 + j
  for (int i = tid; i < 768 * 256; i += stride) {
    const int j = i & 7, ln = (i >> 3) & 63, kc = (i >> 9) & 7, t12 = i >> 12;
    const int tt = t12 % 6, wvv = t12 / 6;
    const int n = (tt >> 1) * 256 + 32 * wvv + (tt & 1) * 16 + (ln & 15);
    const int k = kc * 32 + (ln >> 4) * 8 + j;
    WhhFrag[i] = f2bf(W_hh[n * 256 + k]);
  }
}

// ---------------------------------------------------------------------------
// GEMM 128x128 (R11, passing) -- used for gemm1 (gi pair-packed) and gemm_u.
// OMODE: 0 = f32 linear, 2 = bf16 gi pair-packed
// ---------------------------------------------------------------------------
template <int OMODE>
__global__ __launch_bounds__(256) void fpp_gemm_bt(
    const short* __restrict__ A, const short* __restrict__ B, void* __restrict__ C,
    const float* __restrict__ bias1, const float* __restrict__ bias2, int bias2_limit,
    const float* __restrict__ rowbias,
    int M, int N, int K, int lda, int ldb, int ldc,
    int MT, int NT, int SUPER, int XCD) {
  int bid = blockIdx.x;
  if (XCD) {
    const int nx = gridDim.x >> 3;
    bid = (bid & 7) * nx + (bid >> 3);
  }
  const int per_super = SUPER * NT;
  const int srow = bid / per_super;
  const int rrem = bid - srow * per_super;
  const int mi = srow * SUPER + (rrem % SUPER);
  const int ni = rrem / SUPER;
  const int m0 = mi * 128, n0 = ni * 128;

  __shared__ __attribute__((aligned(16))) short As[2][128 * 64];
  __shared__ __attribute__((aligned(16))) short Bs[2][128 * 64];

  const int tid = threadIdx.x;
  const int lane = tid & 63;
  const int wv = tid >> 6;
  const int wr = wv >> 1, wc = wv & 1;

  f32x4 acc[4][4];
#pragma unroll
  for (int a_ = 0; a_ < 4; ++a_)
#pragma unroll
    for (int b_ = 0; b_ < 4; ++b_) acc[a_][b_] = f32x4{0.f, 0.f, 0.f, 0.f};

  auto stage = [&](int buf, int k0) {
#pragma unroll
    for (int c = 0; c < 4; ++c) {
      const int chunk = c * 256 + tid;
      const int row = chunk >> 3, kc8 = chunk & 7;
      int gr = m0 + row; gr = (gr < M) ? gr : (M - 1);
      gload_lds16(A + (int64_t)gr * lda + k0 + kc8 * 8,
                  (char*)&As[buf][0] + (c * 256 + wv * 64) * 16);
    }
#pragma unroll
    for (int c = 0; c < 4; ++c) {
      const int chunk = c * 256 + tid;
      const int row = chunk >> 3, kc8 = chunk & 7;
      int gn = n0 + row; gn = (gn < N) ? gn : (N - 1);
      gload_lds16(B + (int64_t)gn * ldb + k0 + kc8 * 8,
                  (char*)&Bs[buf][0] + (c * 256 + wv * 64) * 16);
    }
  };

  const int nk = K >> 6;
  stage(0, 0);
  asm volatile("s_waitcnt vmcnt(0)" ::: "memory");
  __syncthreads();
  for (int ks = 0; ks < nk; ++ks) {
    const int cur = ks & 1;
    if (ks + 1 < nk) stage(cur ^ 1, (ks + 1) << 6);
#pragma unroll
    for (int kk = 0; kk < 2; ++kk) {
      bf16x8 af[4], bfr[4];
#pragma unroll
      for (int mt = 0; mt < 4; ++mt)
        af[mt] = *(const bf16x8*)&As[cur][(wr * 64 + mt * 16 + (lane & 15)) * 64 +
                                          kk * 32 + (lane >> 4) * 8];
#pragma unroll
      for (int nt = 0; nt < 4; ++nt)
        bfr[nt] = *(const bf16x8*)&Bs[cur][(wc * 64 + nt * 16 + (lane & 15)) * 64 +
                                           kk * 32 + (lane >> 4) * 8];
#pragma unroll
      for (int mt = 0; mt < 4; ++mt)
#pragma unroll
        for (int nt = 0; nt < 4; ++nt)
          acc[mt][nt] = __builtin_amdgcn_mfma_f32_16x16x32_bf16(
              af[mt], bfr[nt], acc[mt][nt], 0, 0, 0);
    }
    asm volatile("s_waitcnt vmcnt(0)" ::: "memory");
    __syncthreads();
  }

#pragma unroll
  for (int nt = 0; nt < 4; ++nt) {
    const int col = n0 + wc * 64 + nt * 16 + (lane & 15);
    if (col >= N) continue;
    float badd = 0.f;
    if (bias1) badd += bias1[col];
    if (bias2 && col < bias2_limit) badd += bias2[col];
#pragma unroll
    for (int mt = 0; mt < 4; ++mt) {
      const int rbase = m0 + wr * 64 + mt * 16 + (lane >> 4) * 4;
#pragma unroll
      for (int r = 0; r < 4; ++r) {
        const int row = rbase + r;
        if (row < M) {
          float v = acc[mt][nt][r] + badd;
          if (OMODE == 0) {
            if (rowbias) v += rowbias[(int64_t)(row & 63) * ldc + col];
            ((float*)C)[(int64_t)row * ldc + col] = v;
          } else {
            const int cc = col & 255;
            const int jj = ((cc >> 5) << 4) + (cc & 15);
            ((short*)C)[(int64_t)row * 1024 + jj * 8 + ((cc >> 4) & 1) * 4 +
                        (col >> 8)] = f2bf(v);
          }
        }
      }
    }
  }
}

// ---------------------------------------------------------------------------
// GEMM 256(M)x128(N) for the fc layer -- WRITE-OVERLAP regime:
//  - 512 threads (8 waves: wr=wv>>1 M-band, wc=wv&1 N-band), single-buffered
//    48KB LDS -> 2 blocks/CU at 4 waves/SIMD (128-VGPR budget; acc=88 fits;
//    R13 lesson: 1024-thread blocks can never be 2/CU without spilling).
//    Block B's MFMA phase hides block A's write-bound epilogue.
//  - T2 XOR-swizzle on staged tiles (verified conflict-free in R12).
//  - LDS-staged epilogue (proven R13/R14): acc -> st[64][132] -> contiguous
//    dwordx4 stores; bias/rowbias as f32x4 L2 loads.
//  - XCD-bijective remap (grid 5056 = 8 x 632).
// ---------------------------------------------------------------------------
#define STW 132
__global__ __launch_bounds__(512) void fpp_gemm256(
    const short* __restrict__ A, const short* __restrict__ B,
    float* __restrict__ C, const float* __restrict__ bias1,
    const float* __restrict__ rowbias,
    int M, int N, int K, int lda, int ldb, int ldc, int NT, int SUPER, int XCD) {
  int bid = blockIdx.x;
  if (XCD) {
    const int nx = gridDim.x >> 3;  // grid divisible by 8
    bid = (bid & 7) * nx + (bid >> 3);
  }
  const int per_super = SUPER * NT;
  const int srow = bid / per_super;
  const int rrem = bid - srow * per_super;
  const int mi = srow * SUPER + (rrem % SUPER);
  const int ni = rrem / SUPER;
  const int m0 = mi * 256, n0 = ni * 128;

  __shared__ __attribute__((aligned(16))) char smem[49152];  // 48 KB
  short* As = (short*)smem;            // 256x64 bf16 = 32 KB
  short* Bs = (short*)(smem + 32768);  // 128x64 bf16 = 16 KB
  float* st = (float*)smem;            // epilogue staging 64 x STW f32 (33.8 KB)

  const int tid = threadIdx.x;
  const int lane = tid & 63;
  const int wv = tid >> 6;          // 0..7
  const int wr = wv >> 1, wc = wv & 1;

  f32x4 acc[4][4];
#pragma unroll
  for (int a_ = 0; a_ < 4; ++a_)
#pragma unroll
    for (int b_ = 0; b_ < 4; ++b_) acc[a_][b_] = f32x4{0.f, 0.f, 0.f, 0.f};

  // stage with pre-swizzled global source (rule #21: LDS dest stays linear)
  auto stage = [&](int k0) {
#pragma unroll
    for (int c = 0; c < 4; ++c) {  // A: 2048 slots / 512 thr
      const int slot = c * 512 + tid;
      const int row = slot >> 3;                 // 0..255
      const int kc8 = (slot & 7) ^ (row & 7);    // inverse swizzle on source
      gload_lds16(A + (int64_t)(m0 + row) * lda + k0 + kc8 * 8,
                  (char*)As + (c * 512 + wv * 64) * 16);
    }
#pragma unroll
    for (int c = 0; c < 2; ++c) {  // B: 1024 slots
      const int slot = c * 512 + tid;
      const int row = slot >> 3;                 // 0..127
      const int kc8 = (slot & 7) ^ (row & 7);
      int gn = n0 + row; gn = (gn < N) ? gn : (N - 1);
      gload_lds16(B + (int64_t)gn * ldb + k0 + kc8 * 8,
                  (char*)Bs + (c * 512 + wv * 64) * 16);
    }
  };

  const int nk = K >> 6;
  for (int ks = 0; ks < nk; ++ks) {
    stage(ks << 6);
    asm volatile("s_waitcnt vmcnt(0)" ::: "memory");
    __syncthreads();  // DMA landed + visible to all waves
#pragma unroll
    for (int kk = 0; kk < 2; ++kk) {
      bf16x8 af[4], bfr[4];
#pragma unroll
      for (int mt = 0; mt < 4; ++mt) {
        const int row = wr * 64 + mt * 16 + (lane & 15);
        const int u = (kk * 4 + (lane >> 4)) ^ (row & 7);  // swizzled read
        af[mt] = *(const bf16x8*)&As[row * 64 + u * 8];
      }
#pragma unroll
      for (int nt = 0; nt < 4; ++nt) {
        const int row = wc * 64 + nt * 16 + (lane & 15);
        const int u = (kk * 4 + (lane >> 4)) ^ (row & 7);
        bfr[nt] = *(const bf16x8*)&Bs[row * 64 + u * 8];
      }
#pragma unroll
      for (int mt = 0; mt < 4; ++mt)
#pragma unroll
        for (int nt = 0; nt < 4; ++nt)
          acc[mt][nt] = __builtin_amdgcn_mfma_f32_16x16x32_bf16(
              af[mt], bfr[nt], acc[mt][nt], 0, 0, 0);
    }
    __syncthreads();  // all LDS reads done before next stage overwrites
  }

  // LDS-staged epilogue: 4 chunks of 64 M-rows. Chunk q: the 2 waves with
  // wr==q stage their acc into st[64][STW]; then all 8 waves store 64x128
  // contiguous (512B per row, dwordx4 per lane) with f32x4 bias/rowbias.
#pragma unroll
  for (int q = 0; q < 4; ++q) {
    if (q) __syncthreads();  // prior chunk's st reads done
    if (wr == q) {
#pragma unroll
      for (int nt = 0; nt < 4; ++nt)
#pragma unroll
        for (int r = 0; r < 4; ++r)
          st[(/*strow*/ 0 + (lane >> 4) * 4 + r + 0) * STW + wc * 64 + nt * 16 +
             (lane & 15)] += 0.f,  // placeholder no-op fold (kept simple below)
          st[((lane >> 4) * 4 + r) * STW + wc * 64 + nt * 16 + (lane & 15)] =
              acc[0][nt][r];
      // write remaining mt sub-tiles (strow = mt*16 + (lane>>4)*4 + r)
#pragma unroll
      for (int mt = 1; mt < 4; ++mt)
#pragma unroll
        for (int nt = 0; nt < 4; ++nt)
#pragma unroll
          for (int r = 0; r < 4; ++r)
            st[(mt * 16 + (lane >> 4) * 4 + r) * STW + wc * 64 + nt * 16 +
               (lane & 15)] = acc[mt][nt][r];
    }
    __syncthreads();
    // cooperative store: 2048 f32x4 slots; each thread 4 slots.
#pragma unroll
    for (int i = 0; i < 4; ++i) {
      const int slot = i * 512 + tid;       // 0..2047
      const int strow = slot >> 5;          // 0..63
      const int sc4 = slot & 31;            // f32x4 index within row
      const int grow = m0 + q * 64 + strow;
      const int col = n0 + (sc4 << 2);
      f32x4 v = *(const f32x4*)&st[strow * STW + (sc4 << 2)];
      if (col + 3 < N) {
        if (bias1) v += *(const f32x4*)&bias1[col];
        if (rowbias) v += *(const f32x4*)&rowbias[(int64_t)(grow & 63) * ldc + col];
        *(f32x4*)&C[(int64_t)grow * ldc + col] = v;
      } else {
#pragma unroll
        for (int e = 0; e < 4; ++e) {
          const int ce = col + e;
          if (ce < N) {
            float vv = v[e];
            if (bias1) vv += bias1[ce];
            if (rowbias) vv += rowbias[(int64_t)(grow & 63) * ldc + ce];
            C[(int64_t)grow * ldc + ce] = vv;
          }
        }
      }
    }
  }
}

// ---------------------------------------------------------------------------
// GRU v2 (R10, passing): 8 blocks x 8 users x 8 waves. tp-split via shfl_xor;
// gi per-lane register prefetch; h double-buffered; one barrier per step.
// ---------------------------------------------------------------------------
__global__ __attribute__((amdgpu_waves_per_eu(2, 2))) __launch_bounds__(512)
void fpp_gru(
    const int* __restrict__ x, const float* __restrict__ h0,
    const short* __restrict__ WhhFrag, const float* __restrict__ b_hh,
    const short* __restrict__ giV, float* __restrict__ out,
    float* __restrict__ hlast) {
  __shared__ __attribute__((aligned(16))) short h_lds[2][16 * 264];  // 16.9 KB
  __shared__ __attribute__((aligned(16))) uint16_t x_lds[256 * 8];   // 4 KB

  const int tid = threadIdx.x;
  const int lane = tid & 63;
  const int wv = tid >> 6;  // wave 0..7
  const int u0 = blockIdx.x * 8;
  const int g = lane >> 4;
  const int lo = lane & 15;
  const int tp = (lane >= 32) ? 1 : 0;  // which 16-col half this lane gates
  const int uh = g & 1;                 // user-half selector: u = uh*4 + r

  for (int i = tid; i < 256 * 8; i += 512)
    x_lds[i] = (uint16_t)x[(i >> 3) * 64 + u0 + (i & 7)];
  // zero h rows 8-15 (both buffers): A-operand rows for nonexistent users
  for (int i = tid; i < 8 * 264; i += 512) {
    h_lds[0][8 * 264 + i] = 0;
    h_lds[1][8 * 264 + i] = 0;
  }

  // preload W_hh B-fragments: 48 coalesced dwordx4 loads (fragment-linear)
  bf16x8 Wf[6][8];
  {
    const bf16x8* wfp = (const bf16x8*)WhhFrag;
#pragma unroll
    for (int tt = 0; tt < 6; ++tt)
#pragma unroll
      for (int kc = 0; kc < 8; ++kc)
        Wf[tt][kc] = wfp[((wv * 6 + tt) * 8 + kc) * 64 + lane];
  }
  // n-gate b_hh for this lane's single column c = 32wv + tp*16 + lo
  const float bhh = b_hh[512 + 32 * wv + tp * 16 + lo];

  // 4 cells per lane: u = uh*4+r, c = 32wv + tp*16 + lo
  const int c_own = 32 * wv + tp * 16 + lo;
  float hreg[4];
#pragma unroll
  for (int r = 0; r < 4; ++r) {
    const int u = uh * 4 + r;
    const float v = h0[(u0 + u) * 256 + c_own];
    hreg[r] = v;
    h_lds[0][u * 264 + c_own] = f2bf(v);
  }

  // gi register prefetch: per lane, 4 x 8B (gates r,z,n for (u, c_own))
  typedef unsigned int uint2v __attribute__((ext_vector_type(2)));
  auto load_gi = [&](uint2v* dst, int ss) {
#pragma unroll
    for (int r = 0; r < 4; ++r) {
      const int u = uh * 4 + r;
      const int xid = x_lds[ss * 8 + u];
      dst[r] = *(const uint2v*)((const char*)giV + (int64_t)xid * 2048 +
                                (wv * 16 + lo) * 16 + tp * 8);
    }
  };

  __syncthreads();  // x_lds + h_lds[0] + zeroed rows visible

  uint2v gcur[4], gnx[4];
  load_gi(gcur, 0);

  for (int s = 0; s < 256; ++s) {
    load_gi(gnx, (s + 1) & 255);  // prefetch next step (wrapped tail: unused)

    const short* hr = h_lds[s & 1];
    short* hw = h_lds[(s + 1) & 1];

    // gh = h @ W_hh^T : 48 MFMAs; D rows 8-15 are zero (A rows zeroed)
    f32x4 acc[6];
#pragma unroll
    for (int tt = 0; tt < 6; ++tt) acc[tt] = f32x4{0.f, 0.f, 0.f, 0.f};
#pragma unroll
    for (int kc = 0; kc < 8; ++kc) {
      const bf16x8 a = *(const bf16x8*)&hr[lo * 264 + kc * 32 + g * 8];
#pragma unroll
      for (int tt = 0; tt < 6; ++tt)
        acc[tt] = __builtin_amdgcn_mfma_f32_16x16x32_bf16(a, Wf[tt][kc], acc[tt], 0, 0, 0);
    }

    // tp-split: odd tiles (tp=1) of lanes<32 -> lanes>=32 via shfl_xor(32).
    float mine[3][4];
#pragma unroll
    for (int G = 0; G < 3; ++G) {
#pragma unroll
      for (int r = 0; r < 4; ++r) {
        const float swv = __shfl_xor(acc[2 * G + 1][r], 32, 64);
        mine[G][r] = (lane < 32) ? acc[2 * G][r] : swv;
      }
    }

    // gates: 4 cells per lane
#pragma unroll
    for (int r = 0; r < 4; ++r) {
      const int u = uh * 4 + r;
      const short4 gv = *(const short4*)&gcur[r];
      const float gir = bf2f(gv.x);
      const float giz = bf2f(gv.y);
      const float gin = bf2f(gv.z);
      const float xr = mine[0][r] + gir;
      const float rr = __builtin_amdgcn_rcpf(1.f + __builtin_amdgcn_exp2f(-1.4426950408889634f * xr));
      const float xz = mine[1][r] + giz;
      const float zz = __builtin_amdgcn_rcpf(1.f + __builtin_amdgcn_exp2f(-1.4426950408889634f * xz));
      float xn = gin + rr * (mine[2][r] + bhh);
      xn = fminf(fmaxf(xn, -12.f), 12.f);
      const float E = __builtin_amdgcn_exp2f(2.8853900817779268f * xn);
      const float nn = (E - 1.f) * __builtin_amdgcn_rcpf(E + 1.f);
      const float hv = nn + zz * (hreg[r] - nn);
      hreg[r] = hv;
      hw[u * 264 + c_own] = f2bf(hv);
      out[((int64_t)s * 64 + u0 + u) * 256 + c_own] = hv;  // store not awaited
    }

    // single per-step barrier: h writes visible; vm ops stay in flight
    asm volatile("s_waitcnt lgkmcnt(0)\n\ts_barrier" ::: "memory");

#pragma unroll
    for (int r = 0; r < 4; ++r) gcur[r] = gnx[r];
  }

#pragma unroll
  for (int r = 0; r < 4; ++r) {
    const int u = uh * 4 + r;
    hlast[(u0 + u) * 256 + c_own] = hreg[r];
  }
}

// ---------------------------------------------------------------------------
// attention: per (u, i-block of 64): loop causal j-blocks; w in LDS; weighted
// sum of GRU hiddens; writes bf16 into A2 (stride 256). f32 vector math.
// ---------------------------------------------------------------------------
__global__ __launch_bounds__(256) void fpp_attn(
    const float* __restrict__ t_g, const float* __restrict__ s_g,
    const float* __restrict__ gout, short* __restrict__ A2) {
  const int u = blockIdx.x;   // 0..63
  const int ib = blockIdx.y;  // 0..3
  const int tid = threadIdx.x;
  const int iloc = tid >> 2;  // 0..63
  const int q = tid & 3;      // h quarter (64 each)

  __shared__ __attribute__((aligned(16))) float out_lds[64][272];  // q-seg stride 68
  __shared__ __attribute__((aligned(16))) float w_lds[64][65];
  __shared__ float ti[64], si0[64], si1[64], tj[64], sj0[64], sj1[64], sum_lds[64];

  if (tid < 64) {
    const int ig = ib * 64 + tid;
    ti[tid] = t_g[ig * 64 + u];
    si0[tid] = s_g[(ig * 64 + u) * 2 + 0];
    si1[tid] = s_g[(ig * 64 + u) * 2 + 1];
    sum_lds[tid] = 0.f;
  }

  f32x4 accv[16];
#pragma unroll
  for (int hh = 0; hh < 16; ++hh) accv[hh] = f32x4{0.f, 0.f, 0.f, 0.f};

  const int igl = ib * 64 + iloc;

  for (int jb = 0; jb <= ib; ++jb) {
    __syncthreads();  // protect LDS vs previous iteration readers
    {
      const int jj = tid >> 2;
      const float* src = gout + ((int64_t)(jb * 64 + jj) * 64 + u) * 256 + q * 64;
#pragma unroll
      for (int hh = 0; hh < 16; ++hh)
        *(f32x4*)&out_lds[jj][q * 68 + hh * 4] = *(const f32x4*)(src + hh * 4);
    }
    if (tid < 64) {
      const int jg = jb * 64 + tid;
      tj[tid] = t_g[jg * 64 + u];
      sj0[tid] = s_g[(jg * 64 + u) * 2 + 0];
      sj1[tid] = s_g[(jg * 64 + u) * 2 + 1];
    }
    __syncthreads();
    {
      const float tiv = ti[iloc], p0 = si0[iloc], p1 = si1[iloc];
#pragma unroll
      for (int jj = 0; jj < 16; ++jj) {
        const int j = q * 16 + jj;
        const int jgl = jb * 64 + j;
        const float dt = tiv - tj[j];
        // f_t = (cos(2*pi*dt)+1)*0.5*exp(-0.1*dt); v_cos takes revolutions
        const float ft = (__builtin_amdgcn_cosf(dt) + 1.f) * 0.5f *
                         __builtin_amdgcn_exp2f(-0.14426950408889634f * dt);
        const float dx = p0 - sj0[j], dy = p1 - sj1[j];
        const float ds = __builtin_amdgcn_sqrtf(dx * dx + dy * dy);
        const float fs = __builtin_amdgcn_exp2f(-144.26950408889634f * ds);
        float wvv = ft * fs + 1e-10f;
        if (jgl > igl) wvv = 0.f;  // causal
        w_lds[iloc][j] = wvv;
      }
    }
    __syncthreads();
    if (tid < 64) {
      float sm = 0.f;
#pragma unroll
      for (int j = 0; j < 64; ++j) sm += w_lds[tid][j];
      sum_lds[tid] += sm;
    }
    for (int j = 0; j < 64; ++j) {
      const float wvv = w_lds[iloc][j];
#pragma unroll
      for (int hh = 0; hh < 16; ++hh) {
        const f32x4 o = *(const f32x4*)&out_lds[j][q * 68 + hh * 4];
        accv[hh] += o * wvv;
      }
    }
  }
  __syncthreads();
  const float inv = 1.f / sum_lds[iloc];
  short* dst = A2 + (int64_t)((ib * 64 + iloc) * 64 + u) * 256 + q * 64;
#pragma unroll
  for (int hh = 0; hh < 16; ++hh) {
    const f32x4 v = accv[hh] * inv;
    short4 sv;
    sv.x = f2bf(v[0]); sv.y = f2bf(v[1]); sv.z = f2bf(v[2]); sv.w = f2bf(v[3]);
    *(short4*)(dst + hh * 4) = sv;
  }
}

// ---------------------------------------------------------------------------
extern "C" void kernel_launch(void* const* d_in, const int* in_sizes, int n_in,
                              void* d_out, int out_size, void* d_ws, size_t ws_size,
                              hipStream_t stream) {
  (void)in_sizes; (void)n_in; (void)out_size; (void)ws_size;
  const int*   x      = (const int*)  d_in[0];
  const float* t      = (const float*)d_in[1];
  const float* s      = (const float*)d_in[2];
  // d_in[3], d_in[4] (y_t, y_s) unused by reference
  const float* h0     = (const float*)d_in[5];
  const int*   au     = (const int*)  d_in[6];
  const float* enc_W  = (const float*)d_in[7];
  const float* user_W = (const float*)d_in[8];
  const float* W_ih   = (const float*)d_in[9];
  const float* W_hh   = (const float*)d_in[10];
  const float* b_ih   = (const float*)d_in[11];
  const float* b_hh   = (const float*)d_in[12];
  const float* fc_W   = (const float*)d_in[13];
  const float* fc_b   = (const float*)d_in[14];

  float* y = (float*)d_out;
  float* hlast = y + Y_ELEMS;

  char* ws = (char*)d_ws;
  short* giV   = (short*)(ws + 0);          // 10000x256x4 bf16, pair-packed
  short* A2    = (short*)(ws + 20480000);   // 16384x256 bf16 (attn out only)
  short* fcWb  = (short*)(ws + 28868608);   // 10000x512 bf16
  short* encWb = (short*)(ws + 39108608);   // 10000x256 bf16
  short* WihB  = (short*)(ws + 44228608);   // 768x256 bf16
  short* uWb   = (short*)(ws + 44621824);   // 64x256 bf16 (gathered p_u)
  float* U     = (float*)(ws + 44654592);   // 64x10000 f32 = p_u @ fc2^T
  float* gout  = (float*)(ws + 47214592);   // 256x64x256 f32 GRU hiddens
  // WhhFrag scratch lives inside d_out's y region (written by prep, read by
  // GRU, overwritten by the final GEMM).
  short* WhhFrag = (short*)(y + 80000000);  // 768x256 bf16, fragment-linear

  fpp_prep<<<1024, 256, 0, stream>>>(enc_W, W_ih, fc_W, user_W, W_hh, au,
                                     encWb, WihB, fcWb, uWb, WhhFrag);
  // giV = enc_W @ W_ih.T + b_ih (+ b_hh for n<512); bf16, pair-packed layout
  fpp_gemm_bt<2><<<79 * 6, 256, 0, stream>>>(
      encWb, WihB, giV, b_ih, b_hh, 512, nullptr,
      10000, 768, 256, 256, 256, 0, 79, 6, 1, 0);
  // U = p_u @ fc_W[:,256:].T  (64 x 10000, f32; no bias)
  fpp_gemm_bt<0><<<79, 256, 0, stream>>>(
      uWb, fcWb + 256, U, nullptr, nullptr, 0, nullptr,
      64, 10000, 256, 256, 512, 10000, 1, 79, 1, 0);
  fpp_gru<<<8, 512, 0, stream>>>(x, h0, WhhFrag, b_hh, giV, gout, hlast);
  fpp_attn<<<dim3(64, 4), 256, 0, stream>>>(t, s, gout, A2);
  // y = attn @ fc_W[:,:256].T + fc_b + U[row&63]  (256x128-tile GEMM, 2/CU)
  fpp_gemm256<<<64 * 79, 512, 0, stream>>>(
      A2, fcWb, y, fc_b, U,
      16384, 10000, 256, 256, 512, 10000, 79, 8, 1);
}

// Round 16
// 711.244 us; speedup vs baseline: 2.5663x; 1.1284x over previous
//
#include <hip/hip_runtime.h>
#include <stdint.h>

// FlashbackPlusPlus: embed->GRU->spatiotemporal causal attention->FC
// S=256 U=64 H=256 V=10000
#define S_LEN 256
#define U_LEN 64
#define H_DIM 256
#define V_DIM 10000
#define Y_ELEMS 163840000LL  // S*U*V

typedef short bf16x8 __attribute__((ext_vector_type(8)));
typedef float f32x4 __attribute__((ext_vector_type(4)));

__device__ __forceinline__ short f2bf(float f) {
  union { float f; uint32_t u; } v; v.f = f;
  uint32_t r = v.u + 0x7FFFu + ((v.u >> 16) & 1u);  // RNE
  return (short)(r >> 16);
}
__device__ __forceinline__ float bf2f(short s) {
  union { uint32_t u; float f; } v; v.u = ((uint32_t)(uint16_t)s) << 16;
  return v.f;
}

// global -> LDS async copy, 16B per lane. LDS dest = wave-uniform base + lane*16.
__device__ __forceinline__ void gload_lds16(const void* g, void* l) {
  __builtin_amdgcn_global_load_lds(
      (const __attribute__((address_space(1))) char*)(uintptr_t)g,
      (__attribute__((address_space(3))) char*)(uintptr_t)l, 16, 0, 0);
}

// ---------------------------------------------------------------------------
// prep: f32->bf16 weight conversions + active-user embedding gather + W_hh
// fragment pack (fragment-linear so the GRU preamble is coalesced dwordx4).
// ---------------------------------------------------------------------------
__global__ __launch_bounds__(256) void fpp_prep(
    const float* __restrict__ enc_W, const float* __restrict__ W_ih,
    const float* __restrict__ fc_W, const float* __restrict__ user_W,
    const float* __restrict__ W_hh, const int* __restrict__ active_user,
    short* __restrict__ encWb, short* __restrict__ WihB,
    short* __restrict__ fcWb, short* __restrict__ uWb,
    short* __restrict__ WhhFrag) {
  const int tid = blockIdx.x * 256 + threadIdx.x;
  const int stride = gridDim.x * 256;
  for (int i = tid; i < V_DIM * H_DIM; i += stride) encWb[i] = f2bf(enc_W[i]);
  for (int i = tid; i < 3 * H_DIM * H_DIM; i += stride) WihB[i] = f2bf(W_ih[i]);
  for (int i = tid; i < V_DIM * 2 * H_DIM; i += stride) fcWb[i] = f2bf(fc_W[i]);
  // uWb[u][k] = user_W[active_user[u]][k]  (64 x 256 bf16)
  for (int i = tid; i < 64 * 256; i += stride) {
    const int u = i >> 8, k = i & 255;
    uWb[i] = f2bf(user_W[(int64_t)active_user[u] * 256 + k]);
  }
  // WhhFrag[i], i = (((wv*6+tt)*8+kc)*64+lane)*8+j ; holds W_hh[n][k] bf16 with
  // n = (tt>>1)*256 + 32*wv + (tt&1)*16 + (lane&15), k = kc*32 + (lane>>4)*8 + j
  for (int i = tid; i < 768 * 256; i += stride) {
    const int j = i & 7, ln = (i >> 3) & 63, kc = (i >> 9) & 7, t12 = i >> 12;
    const int tt = t12 % 6, wvv = t12 / 6;
    const int n = (tt >> 1) * 256 + 32 * wvv + (tt & 1) * 16 + (ln & 15);
    const int k = kc * 32 + (ln >> 4) * 8 + j;
    WhhFrag[i] = f2bf(W_hh[n * 256 + k]);
  }
}

// ---------------------------------------------------------------------------
// GEMM 128x128 (R11, passing) -- used for gemm1 (gi pair-packed) and gemm_u.
// OMODE: 0 = f32 linear, 2 = bf16 gi pair-packed
// ---------------------------------------------------------------------------
template <int OMODE>
__global__ __launch_bounds__(256) void fpp_gemm_bt(
    const short* __restrict__ A, const short* __restrict__ B, void* __restrict__ C,
    const float* __restrict__ bias1, const float* __restrict__ bias2, int bias2_limit,
    const float* __restrict__ rowbias,
    int M, int N, int K, int lda, int ldb, int ldc,
    int MT, int NT, int SUPER, int XCD) {
  int bid = blockIdx.x;
  if (XCD) {
    const int nx = gridDim.x >> 3;
    bid = (bid & 7) * nx + (bid >> 3);
  }
  const int per_super = SUPER * NT;
  const int srow = bid / per_super;
  const int rrem = bid - srow * per_super;
  const int mi = srow * SUPER + (rrem % SUPER);
  const int ni = rrem / SUPER;
  const int m0 = mi * 128, n0 = ni * 128;

  __shared__ __attribute__((aligned(16))) short As[2][128 * 64];
  __shared__ __attribute__((aligned(16))) short Bs[2][128 * 64];

  const int tid = threadIdx.x;
  const int lane = tid & 63;
  const int wv = tid >> 6;
  const int wr = wv >> 1, wc = wv & 1;

  f32x4 acc[4][4];
#pragma unroll
  for (int a_ = 0; a_ < 4; ++a_)
#pragma unroll
    for (int b_ = 0; b_ < 4; ++b_) acc[a_][b_] = f32x4{0.f, 0.f, 0.f, 0.f};

  auto stage = [&](int buf, int k0) {
#pragma unroll
    for (int c = 0; c < 4; ++c) {
      const int chunk = c * 256 + tid;
      const int row = chunk >> 3, kc8 = chunk & 7;
      int gr = m0 + row; gr = (gr < M) ? gr : (M - 1);
      gload_lds16(A + (int64_t)gr * lda + k0 + kc8 * 8,
                  (char*)&As[buf][0] + (c * 256 + wv * 64) * 16);
    }
#pragma unroll
    for (int c = 0; c < 4; ++c) {
      const int chunk = c * 256 + tid;
      const int row = chunk >> 3, kc8 = chunk & 7;
      int gn = n0 + row; gn = (gn < N) ? gn : (N - 1);
      gload_lds16(B + (int64_t)gn * ldb + k0 + kc8 * 8,
                  (char*)&Bs[buf][0] + (c * 256 + wv * 64) * 16);
    }
  };

  const int nk = K >> 6;
  stage(0, 0);
  asm volatile("s_waitcnt vmcnt(0)" ::: "memory");
  __syncthreads();
  for (int ks = 0; ks < nk; ++ks) {
    const int cur = ks & 1;
    if (ks + 1 < nk) stage(cur ^ 1, (ks + 1) << 6);
#pragma unroll
    for (int kk = 0; kk < 2; ++kk) {
      bf16x8 af[4], bfr[4];
#pragma unroll
      for (int mt = 0; mt < 4; ++mt)
        af[mt] = *(const bf16x8*)&As[cur][(wr * 64 + mt * 16 + (lane & 15)) * 64 +
                                          kk * 32 + (lane >> 4) * 8];
#pragma unroll
      for (int nt = 0; nt < 4; ++nt)
        bfr[nt] = *(const bf16x8*)&Bs[cur][(wc * 64 + nt * 16 + (lane & 15)) * 64 +
                                           kk * 32 + (lane >> 4) * 8];
#pragma unroll
      for (int mt = 0; mt < 4; ++mt)
#pragma unroll
        for (int nt = 0; nt < 4; ++nt)
          acc[mt][nt] = __builtin_amdgcn_mfma_f32_16x16x32_bf16(
              af[mt], bfr[nt], acc[mt][nt], 0, 0, 0);
    }
    asm volatile("s_waitcnt vmcnt(0)" ::: "memory");
    __syncthreads();
  }

#pragma unroll
  for (int nt = 0; nt < 4; ++nt) {
    const int col = n0 + wc * 64 + nt * 16 + (lane & 15);
    if (col >= N) continue;
    float badd = 0.f;
    if (bias1) badd += bias1[col];
    if (bias2 && col < bias2_limit) badd += bias2[col];
#pragma unroll
    for (int mt = 0; mt < 4; ++mt) {
      const int rbase = m0 + wr * 64 + mt * 16 + (lane >> 4) * 4;
#pragma unroll
      for (int r = 0; r < 4; ++r) {
        const int row = rbase + r;
        if (row < M) {
          float v = acc[mt][nt][r] + badd;
          if (OMODE == 0) {
            if (rowbias) v += rowbias[(int64_t)(row & 63) * ldc + col];
            ((float*)C)[(int64_t)row * ldc + col] = v;
          } else {
            const int cc = col & 255;
            const int jj = ((cc >> 5) << 4) + (cc & 15);
            ((short*)C)[(int64_t)row * 1024 + jj * 8 + ((cc >> 4) & 1) * 4 +
                        (col >> 8)] = f2bf(v);
          }
        }
      }
    }
  }
}

// ---------------------------------------------------------------------------
// GEMM 256(M)x128(N) for the fc layer -- WRITE-OVERLAP regime:
//  - 512 threads (8 waves), single-buffered 48KB LDS -> 2-3 blocks/CU.
//  - T2 XOR-swizzle on staged tiles (bank-conflict-free ds_read_b128).
//  - LDS-staged epilogue: acc -> st[64][132] -> contiguous dwordx4 stores.
//  - y stores are NON-TEMPORAL (write-once-never-read): bypass L2 write-alloc
//    so the 756MB store stream stops evicting the L2-resident A2 panels
//    (R12 FETCH_SIZE=94MB >> 21MB inputs was the eviction signature).
//  - fc_b pre-folded into rowbias U (gemm_u bias1=fc_b) -> 1 load per slot.
//  - XCD-bijective remap (grid 5056 = 8 x 632).
// ---------------------------------------------------------------------------
#define STW 132
__global__ __launch_bounds__(512) void fpp_gemm256(
    const short* __restrict__ A, const short* __restrict__ B,
    float* __restrict__ C, const float* __restrict__ bias1,
    const float* __restrict__ rowbias,
    int M, int N, int K, int lda, int ldb, int ldc, int NT, int SUPER, int XCD) {
  int bid = blockIdx.x;
  if (XCD) {
    const int nx = gridDim.x >> 3;  // grid divisible by 8
    bid = (bid & 7) * nx + (bid >> 3);
  }
  const int per_super = SUPER * NT;
  const int srow = bid / per_super;
  const int rrem = bid - srow * per_super;
  const int mi = srow * SUPER + (rrem % SUPER);
  const int ni = rrem / SUPER;
  const int m0 = mi * 256, n0 = ni * 128;

  __shared__ __attribute__((aligned(16))) char smem[49152];  // 48 KB
  short* As = (short*)smem;            // 256x64 bf16 = 32 KB
  short* Bs = (short*)(smem + 32768);  // 128x64 bf16 = 16 KB
  float* st = (float*)smem;            // epilogue staging 64 x STW f32 (33.8 KB)

  const int tid = threadIdx.x;
  const int lane = tid & 63;
  const int wv = tid >> 6;          // 0..7
  const int wr = wv >> 1, wc = wv & 1;

  f32x4 acc[4][4];
#pragma unroll
  for (int a_ = 0; a_ < 4; ++a_)
#pragma unroll
    for (int b_ = 0; b_ < 4; ++b_) acc[a_][b_] = f32x4{0.f, 0.f, 0.f, 0.f};

  // stage with pre-swizzled global source (rule #21: LDS dest stays linear)
  auto stage = [&](int k0) {
#pragma unroll
    for (int c = 0; c < 4; ++c) {  // A: 2048 slots / 512 thr
      const int slot = c * 512 + tid;
      const int row = slot >> 3;                 // 0..255
      const int kc8 = (slot & 7) ^ (row & 7);    // inverse swizzle on source
      gload_lds16(A + (int64_t)(m0 + row) * lda + k0 + kc8 * 8,
                  (char*)As + (c * 512 + wv * 64) * 16);
    }
#pragma unroll
    for (int c = 0; c < 2; ++c) {  // B: 1024 slots
      const int slot = c * 512 + tid;
      const int row = slot >> 3;                 // 0..127
      const int kc8 = (slot & 7) ^ (row & 7);
      int gn = n0 + row; gn = (gn < N) ? gn : (N - 1);
      gload_lds16(B + (int64_t)gn * ldb + k0 + kc8 * 8,
                  (char*)Bs + (c * 512 + wv * 64) * 16);
    }
  };

  const int nk = K >> 6;
  for (int ks = 0; ks < nk; ++ks) {
    stage(ks << 6);
    asm volatile("s_waitcnt vmcnt(0)" ::: "memory");
    __syncthreads();  // DMA landed + visible to all waves
#pragma unroll
    for (int kk = 0; kk < 2; ++kk) {
      bf16x8 af[4], bfr[4];
#pragma unroll
      for (int mt = 0; mt < 4; ++mt) {
        const int row = wr * 64 + mt * 16 + (lane & 15);
        const int u = (kk * 4 + (lane >> 4)) ^ (row & 7);  // swizzled read
        af[mt] = *(const bf16x8*)&As[row * 64 + u * 8];
      }
#pragma unroll
      for (int nt = 0; nt < 4; ++nt) {
        const int row = wc * 64 + nt * 16 + (lane & 15);
        const int u = (kk * 4 + (lane >> 4)) ^ (row & 7);
        bfr[nt] = *(const bf16x8*)&Bs[row * 64 + u * 8];
      }
#pragma unroll
      for (int mt = 0; mt < 4; ++mt)
#pragma unroll
        for (int nt = 0; nt < 4; ++nt)
          acc[mt][nt] = __builtin_amdgcn_mfma_f32_16x16x32_bf16(
              af[mt], bfr[nt], acc[mt][nt], 0, 0, 0);
    }
    __syncthreads();  // all LDS reads done before next stage overwrites
  }

  // LDS-staged epilogue: 4 chunks of 64 M-rows. Chunk q: the 2 waves with
  // wr==q stage their acc into st[64][STW]; then all 8 waves store 64x128
  // contiguous (512B per row, dwordx4 per lane) with f32x4 rowbias loads.
#pragma unroll
  for (int q = 0; q < 4; ++q) {
    if (q) __syncthreads();  // prior chunk's st reads done
    if (wr == q) {
#pragma unroll
      for (int mt = 0; mt < 4; ++mt)
#pragma unroll
        for (int nt = 0; nt < 4; ++nt)
#pragma unroll
          for (int r = 0; r < 4; ++r)
            st[(mt * 16 + (lane >> 4) * 4 + r) * STW + wc * 64 + nt * 16 +
               (lane & 15)] = acc[mt][nt][r];
    }
    __syncthreads();
    // cooperative store: 2048 f32x4 slots; each thread 4 slots.
#pragma unroll
    for (int i = 0; i < 4; ++i) {
      const int slot = i * 512 + tid;       // 0..2047
      const int strow = slot >> 5;          // 0..63
      const int sc4 = slot & 31;            // f32x4 index within row
      const int grow = m0 + q * 64 + strow;
      const int col = n0 + (sc4 << 2);
      f32x4 v = *(const f32x4*)&st[strow * STW + (sc4 << 2)];
      if (col + 3 < N) {
        if (bias1) v += *(const f32x4*)&bias1[col];
        if (rowbias) v += *(const f32x4*)&rowbias[(int64_t)(grow & 63) * ldc + col];
        __builtin_nontemporal_store(v, (f32x4*)&C[(int64_t)grow * ldc + col]);
      } else {
#pragma unroll
        for (int e = 0; e < 4; ++e) {
          const int ce = col + e;
          if (ce < N) {
            float vv = v[e];
            if (bias1) vv += bias1[ce];
            if (rowbias) vv += rowbias[(int64_t)(grow & 63) * ldc + ce];
            __builtin_nontemporal_store(vv, &C[(int64_t)grow * ldc + ce]);
          }
        }
      }
    }
  }
}

// ---------------------------------------------------------------------------
// GRU v2 (R10, passing): 8 blocks x 8 users x 8 waves. tp-split via shfl_xor;
// gi per-lane register prefetch; h double-buffered; one barrier per step.
// ---------------------------------------------------------------------------
__global__ __attribute__((amdgpu_waves_per_eu(2, 2))) __launch_bounds__(512)
void fpp_gru(
    const int* __restrict__ x, const float* __restrict__ h0,
    const short* __restrict__ WhhFrag, const float* __restrict__ b_hh,
    const short* __restrict__ giV, float* __restrict__ out,
    float* __restrict__ hlast) {
  __shared__ __attribute__((aligned(16))) short h_lds[2][16 * 264];  // 16.9 KB
  __shared__ __attribute__((aligned(16))) uint16_t x_lds[256 * 8];   // 4 KB

  const int tid = threadIdx.x;
  const int lane = tid & 63;
  const int wv = tid >> 6;  // wave 0..7
  const int u0 = blockIdx.x * 8;
  const int g = lane >> 4;
  const int lo = lane & 15;
  const int tp = (lane >= 32) ? 1 : 0;  // which 16-col half this lane gates
  const int uh = g & 1;                 // user-half selector: u = uh*4 + r

  for (int i = tid; i < 256 * 8; i += 512)
    x_lds[i] = (uint16_t)x[(i >> 3) * 64 + u0 + (i & 7)];
  // zero h rows 8-15 (both buffers): A-operand rows for nonexistent users
  for (int i = tid; i < 8 * 264; i += 512) {
    h_lds[0][8 * 264 + i] = 0;
    h_lds[1][8 * 264 + i] = 0;
  }

  // preload W_hh B-fragments: 48 coalesced dwordx4 loads (fragment-linear)
  bf16x8 Wf[6][8];
  {
    const bf16x8* wfp = (const bf16x8*)WhhFrag;
#pragma unroll
    for (int tt = 0; tt < 6; ++tt)
#pragma unroll
      for (int kc = 0; kc < 8; ++kc)
        Wf[tt][kc] = wfp[((wv * 6 + tt) * 8 + kc) * 64 + lane];
  }
  // n-gate b_hh for this lane's single column c = 32wv + tp*16 + lo
  const float bhh = b_hh[512 + 32 * wv + tp * 16 + lo];

  // 4 cells per lane: u = uh*4+r, c = 32wv + tp*16 + lo
  const int c_own = 32 * wv + tp * 16 + lo;
  float hreg[4];
#pragma unroll
  for (int r = 0; r < 4; ++r) {
    const int u = uh * 4 + r;
    const float v = h0[(u0 + u) * 256 + c_own];
    hreg[r] = v;
    h_lds[0][u * 264 + c_own] = f2bf(v);
  }

  // gi register prefetch: per lane, 4 x 8B (gates r,z,n for (u, c_own))
  typedef unsigned int uint2v __attribute__((ext_vector_type(2)));
  auto load_gi = [&](uint2v* dst, int ss) {
#pragma unroll
    for (int r = 0; r < 4; ++r) {
      const int u = uh * 4 + r;
      const int xid = x_lds[ss * 8 + u];
      dst[r] = *(const uint2v*)((const char*)giV + (int64_t)xid * 2048 +
                                (wv * 16 + lo) * 16 + tp * 8);
    }
  };

  __syncthreads();  // x_lds + h_lds[0] + zeroed rows visible

  uint2v gcur[4], gnx[4];
  load_gi(gcur, 0);

  for (int s = 0; s < 256; ++s) {
    load_gi(gnx, (s + 1) & 255);  // prefetch next step (wrapped tail: unused)

    const short* hr = h_lds[s & 1];
    short* hw = h_lds[(s + 1) & 1];

    // gh = h @ W_hh^T : 48 MFMAs; D rows 8-15 are zero (A rows zeroed)
    f32x4 acc[6];
#pragma unroll
    for (int tt = 0; tt < 6; ++tt) acc[tt] = f32x4{0.f, 0.f, 0.f, 0.f};
#pragma unroll
    for (int kc = 0; kc < 8; ++kc) {
      const bf16x8 a = *(const bf16x8*)&hr[lo * 264 + kc * 32 + g * 8];
#pragma unroll
      for (int tt = 0; tt < 6; ++tt)
        acc[tt] = __builtin_amdgcn_mfma_f32_16x16x32_bf16(a, Wf[tt][kc], acc[tt], 0, 0, 0);
    }

    // tp-split: odd tiles (tp=1) of lanes<32 -> lanes>=32 via shfl_xor(32).
    float mine[3][4];
#pragma unroll
    for (int G = 0; G < 3; ++G) {
#pragma unroll
      for (int r = 0; r < 4; ++r) {
        const float swv = __shfl_xor(acc[2 * G + 1][r], 32, 64);
        mine[G][r] = (lane < 32) ? acc[2 * G][r] : swv;
      }
    }

    // gates: 4 cells per lane
#pragma unroll
    for (int r = 0; r < 4; ++r) {
      const int u = uh * 4 + r;
      const short4 gv = *(const short4*)&gcur[r];
      const float gir = bf2f(gv.x);
      const float giz = bf2f(gv.y);
      const float gin = bf2f(gv.z);
      const float xr = mine[0][r] + gir;
      const float rr = __builtin_amdgcn_rcpf(1.f + __builtin_amdgcn_exp2f(-1.4426950408889634f * xr));
      const float xz = mine[1][r] + giz;
      const float zz = __builtin_amdgcn_rcpf(1.f + __builtin_amdgcn_exp2f(-1.4426950408889634f * xz));
      float xn = gin + rr * (mine[2][r] + bhh);
      xn = fminf(fmaxf(xn, -12.f), 12.f);
      const float E = __builtin_amdgcn_exp2f(2.8853900817779268f * xn);
      const float nn = (E - 1.f) * __builtin_amdgcn_rcpf(E + 1.f);
      const float hv = nn + zz * (hreg[r] - nn);
      hreg[r] = hv;
      hw[u * 264 + c_own] = f2bf(hv);
      out[((int64_t)s * 64 + u0 + u) * 256 + c_own] = hv;  // store not awaited
    }

    // single per-step barrier: h writes visible; vm ops stay in flight
    asm volatile("s_waitcnt lgkmcnt(0)\n\ts_barrier" ::: "memory");

#pragma unroll
    for (int r = 0; r < 4; ++r) gcur[r] = gnx[r];
  }

#pragma unroll
  for (int r = 0; r < 4; ++r) {
    const int u = uh * 4 + r;
    hlast[(u0 + u) * 256 + c_own] = hreg[r];
  }
}

// ---------------------------------------------------------------------------
// attention: per (u, i-block of 64): loop causal j-blocks; w in LDS; weighted
// sum of GRU hiddens; writes bf16 into A2 (stride 256). f32 vector math.
// ---------------------------------------------------------------------------
__global__ __launch_bounds__(256) void fpp_attn(
    const float* __restrict__ t_g, const float* __restrict__ s_g,
    const float* __restrict__ gout, short* __restrict__ A2) {
  const int u = blockIdx.x;   // 0..63
  const int ib = blockIdx.y;  // 0..3
  const int tid = threadIdx.x;
  const int iloc = tid >> 2;  // 0..63
  const int q = tid & 3;      // h quarter (64 each)

  __shared__ __attribute__((aligned(16))) float out_lds[64][272];  // q-seg stride 68
  __shared__ __attribute__((aligned(16))) float w_lds[64][65];
  __shared__ float ti[64], si0[64], si1[64], tj[64], sj0[64], sj1[64], sum_lds[64];

  if (tid < 64) {
    const int ig = ib * 64 + tid;
    ti[tid] = t_g[ig * 64 + u];
    si0[tid] = s_g[(ig * 64 + u) * 2 + 0];
    si1[tid] = s_g[(ig * 64 + u) * 2 + 1];
    sum_lds[tid] = 0.f;
  }

  f32x4 accv[16];
#pragma unroll
  for (int hh = 0; hh < 16; ++hh) accv[hh] = f32x4{0.f, 0.f, 0.f, 0.f};

  const int igl = ib * 64 + iloc;

  for (int jb = 0; jb <= ib; ++jb) {
    __syncthreads();  // protect LDS vs previous iteration readers
    {
      const int jj = tid >> 2;
      const float* src = gout + ((int64_t)(jb * 64 + jj) * 64 + u) * 256 + q * 64;
#pragma unroll
      for (int hh = 0; hh < 16; ++hh)
        *(f32x4*)&out_lds[jj][q * 68 + hh * 4] = *(const f32x4*)(src + hh * 4);
    }
    if (tid < 64) {
      const int jg = jb * 64 + tid;
      tj[tid] = t_g[jg * 64 + u];
      sj0[tid] = s_g[(jg * 64 + u) * 2 + 0];
      sj1[tid] = s_g[(jg * 64 + u) * 2 + 1];
    }
    __syncthreads();
    {
      const float tiv = ti[iloc], p0 = si0[iloc], p1 = si1[iloc];
#pragma unroll
      for (int jj = 0; jj < 16; ++jj) {
        const int j = q * 16 + jj;
        const int jgl = jb * 64 + j;
        const float dt = tiv - tj[j];
        // f_t = (cos(2*pi*dt)+1)*0.5*exp(-0.1*dt); v_cos takes revolutions
        const float ft = (__builtin_amdgcn_cosf(dt) + 1.f) * 0.5f *
                         __builtin_amdgcn_exp2f(-0.14426950408889634f * dt);
        const float dx = p0 - sj0[j], dy = p1 - sj1[j];
        const float ds = __builtin_amdgcn_sqrtf(dx * dx + dy * dy);
        const float fs = __builtin_amdgcn_exp2f(-144.26950408889634f * ds);
        float wvv = ft * fs + 1e-10f;
        if (jgl > igl) wvv = 0.f;  // causal
        w_lds[iloc][j] = wvv;
      }
    }
    __syncthreads();
    if (tid < 64) {
      float sm = 0.f;
#pragma unroll
      for (int j = 0; j < 64; ++j) sm += w_lds[tid][j];
      sum_lds[tid] += sm;
    }
    for (int j = 0; j < 64; ++j) {
      const float wvv = w_lds[iloc][j];
#pragma unroll
      for (int hh = 0; hh < 16; ++hh) {
        const f32x4 o = *(const f32x4*)&out_lds[j][q * 68 + hh * 4];
        accv[hh] += o * wvv;
      }
    }
  }
  __syncthreads();
  const float inv = 1.f / sum_lds[iloc];
  short* dst = A2 + (int64_t)((ib * 64 + iloc) * 64 + u) * 256 + q * 64;
#pragma unroll
  for (int hh = 0; hh < 16; ++hh) {
    const f32x4 v = accv[hh] * inv;
    short4 sv;
    sv.x = f2bf(v[0]); sv.y = f2bf(v[1]); sv.z = f2bf(v[2]); sv.w = f2bf(v[3]);
    *(short4*)(dst + hh * 4) = sv;
  }
}

// ---------------------------------------------------------------------------
extern "C" void kernel_launch(void* const* d_in, const int* in_sizes, int n_in,
                              void* d_out, int out_size, void* d_ws, size_t ws_size,
                              hipStream_t stream) {
  (void)in_sizes; (void)n_in; (void)out_size; (void)ws_size;
  const int*   x      = (const int*)  d_in[0];
  const float* t      = (const float*)d_in[1];
  const float* s      = (const float*)d_in[2];
  // d_in[3], d_in[4] (y_t, y_s) unused by reference
  const float* h0     = (const float*)d_in[5];
  const int*   au     = (const int*)  d_in[6];
  const float* enc_W  = (const float*)d_in[7];
  const float* user_W = (const float*)d_in[8];
  const float* W_ih   = (const float*)d_in[9];
  const float* W_hh   = (const float*)d_in[10];
  const float* b_ih   = (const float*)d_in[11];
  const float* b_hh   = (const float*)d_in[12];
  const float* fc_W   = (const float*)d_in[13];
  const float* fc_b   = (const float*)d_in[14];

  float* y = (float*)d_out;
  float* hlast = y + Y_ELEMS;

  char* ws = (char*)d_ws;
  short* giV   = (short*)(ws + 0);          // 10000x256x4 bf16, pair-packed
  short* A2    = (short*)(ws + 20480000);   // 16384x256 bf16 (attn out only)
  short* fcWb  = (short*)(ws + 28868608);   // 10000x512 bf16
  short* encWb = (short*)(ws + 39108608);   // 10000x256 bf16
  short* WihB  = (short*)(ws + 44228608);   // 768x256 bf16
  short* uWb   = (short*)(ws + 44621824);   // 64x256 bf16 (gathered p_u)
  float* U     = (float*)(ws + 44654592);   // 64x10000 f32 = p_u @ fc2^T + fc_b
  float* gout  = (float*)(ws + 47214592);   // 256x64x256 f32 GRU hiddens
  // WhhFrag scratch lives inside d_out's y region (written by prep, read by
  // GRU, overwritten by the final GEMM).
  short* WhhFrag = (short*)(y + 80000000);  // 768x256 bf16, fragment-linear

  fpp_prep<<<1024, 256, 0, stream>>>(enc_W, W_ih, fc_W, user_W, W_hh, au,
                                     encWb, WihB, fcWb, uWb, WhhFrag);
  // giV = enc_W @ W_ih.T + b_ih (+ b_hh for n<512); bf16, pair-packed layout
  fpp_gemm_bt<2><<<79 * 6, 256, 0, stream>>>(
      encWb, WihB, giV, b_ih, b_hh, 512, nullptr,
      10000, 768, 256, 256, 256, 0, 79, 6, 1, 0);
  // U = p_u @ fc_W[:,256:].T + fc_b  (64 x 10000, f32; fc_b folded here)
  fpp_gemm_bt<0><<<79, 256, 0, stream>>>(
      uWb, fcWb + 256, U, fc_b, nullptr, 0, nullptr,
      64, 10000, 256, 256, 512, 10000, 1, 79, 1, 0);
  fpp_gru<<<8, 512, 0, stream>>>(x, h0, WhhFrag, b_hh, giV, gout, hlast);
  fpp_attn<<<dim3(64, 4), 256, 0, stream>>>(t, s, gout, A2);
  // y = attn @ fc_W[:,:256].T + U[row&63]  (256x128-tile GEMM, nt stores)
  fpp_gemm256<<<64 * 79, 512, 0, stream>>>(
      A2, fcWb, y, nullptr, U,
      16384, 10000, 256, 256, 512, 10000, 79, 8, 1);
}